// Round 6
// baseline (507.476 us; speedup 1.0000x reference)
//
#include <hip/hip_runtime.h>
#include <math.h>

typedef _Float16 f16x8 __attribute__((ext_vector_type(8)));
typedef _Float16 f16x2 __attribute__((ext_vector_type(2)));
typedef float f32x4 __attribute__((ext_vector_type(4)));

namespace {
constexpr int B_ = 16, C_ = 128, H_ = 96, W_ = 96;
constexpr int HW_ = H_ * W_;
constexpr int G_ = 4, S_ = 2;
constexpr int CO_ = 32;        // offset channels
constexpr int COUT_ = 64;
constexpr int HO_ = 192, WO_ = 192;
constexpr int CPG_ = C_ / G_;  // 32 channels per sampling group
constexpr int TH_ = 16, TW_ = 16;
constexpr int HALO_H = TH_ + 2, HALO_W = TW_ + 2;
constexpr int NPOS = HALO_H * HALO_W;   // 324
constexpr int UPS_F = 34;    // up row stride (f16): word-stride 17 -> conflict-free
constexpr int UP_BYTES = NPOS * UPS_F * 2;         // 22032
constexpr int Y8_BYTES = 256 * 8 * 2;              // 4096 (8 ch/quarter, 16B rows)
constexpr int POOL_BYTES = UP_BYTES + Y8_BYTES;    // 26128 (>= 16*257*4 clds overlay)

// ws float offsets
constexpr size_t WS_OFF1   = 0;                                   // [B,32,96,96]
constexpr size_t WS_COORDS = (size_t)B_ * CO_ * HW_;              // [B,G,HO,WO,2]
constexpr size_t WS_WPWH   = WS_COORDS + (size_t)B_ * G_ * HO_ * WO_ * 2;  // f16[8192]
constexpr size_t WS_WO1T   = WS_WPWH + (C_ * COUT_) / 2;          // f32[128*32]
constexpr size_t WS_WO2T   = WS_WO1T + C_ * CO_;                  // f32[288*32]
constexpr size_t WS_WDWS   = WS_WO2T + CO_ * 9 * CO_;             // f32[9*128]
constexpr size_t WS_BIAS2  = WS_WDWS + 9 * C_;                    // f32[128]

constexpr int PREP_N = C_ * COUT_ + C_ * CO_ + CO_ * CO_ * 9 + 9 * C_ + C_;
}

// --- Kernel P: Wpw->fp16; Wo1/Wo2 transposes; BN-folded dw weights + bias ---
__global__ __launch_bounds__(256) void k_prep(
    const float* __restrict__ Wpw, const float* __restrict__ Wo1,
    const float* __restrict__ Wo2, const float* __restrict__ Wdw,
    const float* __restrict__ bn_gamma, const float* __restrict__ bn_beta,
    const float* __restrict__ bn_mean, const float* __restrict__ bn_var,
    _Float16* __restrict__ wpwH, float* __restrict__ wo1T,
    float* __restrict__ wo2T, float* __restrict__ wdwS,
    float* __restrict__ bias2) {
  int i = blockIdx.x * 256 + threadIdx.x;
  if (i < C_ * COUT_) {
    wpwH[i] = (_Float16)Wpw[i];
  } else if (i < C_ * COUT_ + C_ * CO_) {
    int j = i - C_ * COUT_;
    int o = j >> 7, c = j & 127;   // Wo1 is [32][128]
    wo1T[c * CO_ + o] = Wo1[j];
  } else if (i < C_ * COUT_ + C_ * CO_ + CO_ * CO_ * 9) {
    int j = i - C_ * COUT_ - C_ * CO_;  // Wo2 is [32][288]
    int o = j / 288, r = j % 288;
    wo2T[r * CO_ + o] = Wo2[j];
  } else if (i < C_ * COUT_ + C_ * CO_ + CO_ * CO_ * 9 + 9 * C_) {
    int j = i - C_ * COUT_ - C_ * CO_ - CO_ * CO_ * 9;  // Wdw is [c][9]
    int c = j / 9, t = j % 9;
    float sc = bn_gamma[c] * rsqrtf(bn_var[c] + 1e-5f);
    wdwS[t * C_ + c] = Wdw[j] * sc;
  } else if (i < PREP_N) {
    int c = i - (C_ * COUT_ + C_ * CO_ + CO_ * CO_ * 9 + 9 * C_);
    float sc = bn_gamma[c] * rsqrtf(bn_var[c] + 1e-5f);
    bias2[c] = bn_beta[c] - bn_mean[c] * sc;
  }
}

// ------- Kernel A: 1x1 conv (128 -> 32) + bias, 1 px/thread --------
__global__ __launch_bounds__(256) void k_off1(const float* __restrict__ x,
                                              const float* __restrict__ wo1T,
                                              const float* __restrict__ bo1,
                                              float* __restrict__ off1) {
  int p = blockIdx.x * 256 + threadIdx.x;  // B*HW threads
  int b = p / HW_, hw = p % HW_;
  float acc[CO_];
#pragma unroll
  for (int o = 0; o < CO_; ++o) acc[o] = bo1[o];  // uniform -> s_load
  const float* xb = x + (size_t)b * C_ * HW_ + hw;
  for (int c = 0; c < C_; ++c) {
    float xv = xb[c * HW_];
    const float* wr = wo1T + c * CO_;  // uniform rows -> s_load
#pragma unroll
    for (int o = 0; o < CO_; ++o) acc[o] = fmaf(xv, wr[o], acc[o]);
  }
  float* ob = off1 + (size_t)b * CO_ * HW_ + hw;
#pragma unroll
  for (int o = 0; o < CO_; ++o) ob[o * HW_] = acc[o];
}

// -- Kernel B: 3x3 dil(2) conv (32->32) -> sample coords, 1 px/thread --
__global__ __launch_bounds__(256) void k_coords(const float* __restrict__ off1,
                                                const float* __restrict__ wo2T,
                                                float* __restrict__ coords) {
  int p = blockIdx.x * 256 + threadIdx.x;
  int b = p / HW_, hw = p % HW_;
  int h = hw / W_, w = hw % W_;
  float acc[CO_];
#pragma unroll
  for (int o = 0; o < CO_; ++o) acc[o] = 0.f;
  const float* ib = off1 + (size_t)b * CO_ * HW_;
#pragma unroll
  for (int ky = 0; ky < 3; ++ky) {
    int hh = h + 2 * (ky - 1);
    if ((unsigned)hh < (unsigned)H_) {
      const float* rbase = ib + hh * W_ + w;
      for (int ci = 0; ci < CO_; ++ci) {
        const float* rp = rbase + ci * HW_;
        float vL = (w >= 2) ? rp[-2] : 0.f;
        float vM = rp[0];
        float vR = (w < W_ - 2) ? rp[2] : 0.f;
        const float* wr = wo2T + (ci * 9 + ky * 3) * CO_;  // uniform -> s_load
#pragma unroll
        for (int o = 0; o < CO_; ++o)
          acc[o] = fmaf(vL, wr[o],
                   fmaf(vM, wr[CO_ + o], fmaf(vR, wr[2 * CO_ + o], acc[o])));
      }
    }
  }
  float cwv = (float)w + sinf((float)M_PI * (float)(w + 1) / (float)W_);
  float chv = (float)h + sinf((float)M_PI * (float)(h + 1) / (float)H_);
  float* cb = coords + (size_t)b * G_ * HO_ * WO_ * 2;
#pragma unroll
  for (int g = 0; g < G_; ++g) {
#pragma unroll
    for (int sh = 0; sh < S_; ++sh) {
#pragma unroll
      for (int sw = 0; sw < S_; ++sw) {
        int idx = g * 4 + sh * 2 + sw;
        float offx = acc[idx] * 0.25f + (sw ? 0.25f : -0.25f);
        float offy = acc[16 + idx] * 0.25f + (sh ? 0.25f : -0.25f);
        float ix = fminf(fmaxf(cwv + offx - 0.5f, 0.f), (float)(W_ - 1));
        float iy = fminf(fmaxf(chv + offy - 0.5f, 0.f), (float)(H_ - 1));
        float2* dst = (float2*)(cb + (((size_t)g * HO_ + 2 * h + sh) * WO_
                                      + 2 * w + sw) * 2);
        *dst = (float2){ix, iy};
      }
    }
  }
}

// -- Kernel C: grid_sample (f16 LDS) + dw3x3+BN+ReLU (4 quarter-passes) + MFMA --
// LDS = 26.1 KB -> 6 blocks/CU. All weight tables read via wave-uniform s_loads.
__global__ __launch_bounds__(256, 6) void k_fused(
    const float* __restrict__ x, const float* __restrict__ coords,
    const _Float16* __restrict__ wpwH, const float* __restrict__ wdwS,
    const float* __restrict__ bias2, const float* __restrict__ bpw,
    float* __restrict__ out) {
  __shared__ __align__(16) unsigned char pool[POOL_BYTES];  // up + ylds8 / clds16
  _Float16 (*up)[UPS_F] = (_Float16(*)[UPS_F])pool;
  _Float16* ylds8 = (_Float16*)(pool + UP_BYTES);  // [256][8], 16 B rows

  constexpr int TILES_W = WO_ / TW_;            // 12
  constexpr int TILES = TILES_W * (HO_ / TH_);  // 144
  int b = blockIdx.x / TILES;
  int t = blockIdx.x % TILES;
  int oh0 = (t / TILES_W) * TH_;
  int ow0 = (t % TILES_W) * TW_;
  int tid = threadIdx.x;
  int py = tid / TW_, px = tid % TW_;
  int lane = tid & 63, wv_ = tid >> 6;
  int lr = lane & 15, lk = lane >> 4;

  f32x4 acc[4][4];
#pragma unroll
  for (int mt = 0; mt < 4; ++mt)
#pragma unroll
    for (int nt = 0; nt < 4; ++nt) acc[mt][nt] = (f32x4){0.f, 0.f, 0.f, 0.f};

  for (int g = 0; g < G_; ++g) {
    __syncthreads();  // protects `up` reuse across g
    const float* xg = x + ((size_t)b * C_ + g * CPG_) * HW_;
    const float* cbase = coords + (((size_t)b * G_ + g) * HO_ * WO_) * 2;
    // ---- sampling: work item = (halo position, channel-octet) ----
    for (int wi = tid; wi < NPOS * 4; wi += 256) {
      int p = wi >> 2, cq = wi & 3;
      int hy = oh0 + p / HALO_W - 1;
      int hx = ow0 + p % HALO_W - 1;
      _Float16* dst = &up[p][cq * 8];
      if (hy < 0 || hy >= HO_ || hx < 0 || hx >= WO_) {
#pragma unroll
        for (int j2 = 0; j2 < 4; ++j2)
          *(f16x2*)&dst[2 * j2] = (f16x2){(_Float16)0.f, (_Float16)0.f};
      } else {
        float2 c2 = *(const float2*)&cbase[((size_t)hy * WO_ + hx) * 2];
        float ix = c2.x, iy = c2.y;
        float x0f = floorf(ix), y0f = floorf(iy);
        float wx = ix - x0f, wy = iy - y0f;
        int x0 = (int)x0f, y0 = (int)y0f;  // already in [0, 95]
        int x1 = min(x0 + 1, W_ - 1);
        int y1 = min(y0 + 1, H_ - 1);
        float w00 = (1.f - wx) * (1.f - wy);
        float w01 = wx * (1.f - wy);
        float w10 = (1.f - wx) * wy;
        float w11 = wx * wy;
        const float* r0 = xg + (size_t)(cq * 8) * HW_ + y0 * W_;
        const float* r1 = xg + (size_t)(cq * 8) * HW_ + y1 * W_;
#pragma unroll
        for (int j2 = 0; j2 < 4; ++j2) {
          int offA = (2 * j2) * HW_, offB = offA + HW_;
          float v0 = w00 * r0[offA + x0] + w01 * r0[offA + x1] +
                     w10 * r1[offA + x0] + w11 * r1[offA + x1];
          float v1 = w00 * r0[offB + x0] + w01 * r0[offB + x1] +
                     w10 * r1[offB + x0] + w11 * r1[offB + x1];
          *(f16x2*)&dst[2 * j2] = (f16x2){(_Float16)v0, (_Float16)v1};
        }
      }
    }
    __syncthreads();

    // ---- dw3x3+BN+ReLU in four 8-channel quarter-passes ----
    f16x8 afr[4];
#pragma unroll
    for (int q = 0; q < 4; ++q) {
      if (q) __syncthreads();  // ylds8 overwrite after prev quarter frag loads
      f16x2 yreg[4];
#pragma unroll
      for (int cp = 0; cp < 4; ++cp) {
        int cl = 2 * cp;                     // channel within quarter
        int c = g * CPG_ + q * 8 + cl;       // global channel (loop-uniform)
        float2 bi = *(const float2*)&bias2[c];        // s_load
        float dw0 = bi.x, dw1 = bi.y;
#pragma unroll
        for (int tt = 0; tt < 9; ++tt) {
          int dy = tt / 3, dx = tt % 3;
          f16x2 pk = *(const f16x2*)&up[(py + dy) * HALO_W + px + dx][q * 8 + cl];
          float2 wv = *(const float2*)&wdwS[tt * C_ + c];  // s_load
          dw0 = fmaf((float)pk.x, wv.x, dw0);
          dw1 = fmaf((float)pk.y, wv.y, dw1);
        }
        yreg[cp] = (f16x2){(_Float16)fmaxf(dw0, 0.f), (_Float16)fmaxf(dw1, 0.f)};
      }
      f16x8 yv;
#pragma unroll
      for (int cp = 0; cp < 4; ++cp) { yv[2 * cp] = yreg[cp].x; yv[2 * cp + 1] = yreg[cp].y; }
      *(f16x8*)&ylds8[tid * 8] = yv;   // one ds_write_b128, contiguous
      __syncthreads();
      if (lk == q) {  // this lane's k-slot lives in this quarter
#pragma unroll
        for (int mt = 0; mt < 4; ++mt)
          afr[mt] = *(const f16x8*)&ylds8[((wv_ * 4 + mt) * 16 + lr) * 8];
      }
    }
    // ---- one K=32 MFMA set per g ----
#pragma unroll
    for (int nt = 0; nt < 4; ++nt) {
      f16x8 bfr = *(const f16x8*)&wpwH[(nt * 16 + lr) * C_ + g * CPG_ + lk * 8];
#pragma unroll
      for (int mt = 0; mt < 4; ++mt)
        acc[mt][nt] = __builtin_amdgcn_mfma_f32_16x16x32_f16(afr[mt], bfr,
                                                             acc[mt][nt], 0, 0, 0);
    }
  }

  // ---- epilogue: 4 rounds of 16 channels via clds16 overlay ----
  float (*clds16)[257] = (float(*)[257])pool;  // [16][257] = 16448 B
  int oh = oh0 + py, ow = ow0 + px;
#pragma unroll
  for (int hq = 0; hq < 4; ++hq) {
    __syncthreads();  // first iter: all waves done with up/ylds8
#pragma unroll
    for (int mt = 0; mt < 4; ++mt) {
#pragma unroll
      for (int r = 0; r < 4; ++r)
        clds16[lr][(wv_ * 4 + mt) * 16 + lk * 4 + r] = acc[mt][hq][r];
    }
    __syncthreads();
#pragma unroll
    for (int i = 0; i < 16; ++i) {
      int o = hq * 16 + i;
      out[(((size_t)b * COUT_ + o) * HO_ + oh) * WO_ + ow] = clds16[i][tid] + bpw[o];
    }
  }
}

extern "C" void kernel_launch(void* const* d_in, const int* in_sizes, int n_in,
                              void* d_out, int out_size, void* d_ws, size_t ws_size,
                              hipStream_t stream) {
  const float* x        = (const float*)d_in[0];
  const float* Wo1      = (const float*)d_in[1];
  const float* bo1      = (const float*)d_in[2];
  const float* Wo2      = (const float*)d_in[3];
  const float* Wdw      = (const float*)d_in[4];
  const float* bn_gamma = (const float*)d_in[5];
  const float* bn_beta  = (const float*)d_in[6];
  const float* bn_mean  = (const float*)d_in[7];
  const float* bn_var   = (const float*)d_in[8];
  const float* Wpw      = (const float*)d_in[9];
  const float* bpw      = (const float*)d_in[10];
  float* out = (float*)d_out;

  float* ws = (float*)d_ws;
  float* off1        = ws + WS_OFF1;
  float* coords      = ws + WS_COORDS;
  _Float16* wpwH     = (_Float16*)(ws + WS_WPWH);
  float* wo1T        = ws + WS_WO1T;
  float* wo2T        = ws + WS_WO2T;
  float* wdwS        = ws + WS_WDWS;
  float* bias2       = ws + WS_BIAS2;

  k_prep  <<<(PREP_N + 255) / 256, 256, 0, stream>>>(
      Wpw, Wo1, Wo2, Wdw, bn_gamma, bn_beta, bn_mean, bn_var,
      wpwH, wo1T, wo2T, wdwS, bias2);
  k_off1  <<<(B_ * HW_) / 256, 256, 0, stream>>>(x, wo1T, bo1, off1);
  k_coords<<<(B_ * HW_) / 256, 256, 0, stream>>>(off1, wo2T, coords);
  k_fused <<<B_ * 144, 256, 0, stream>>>(x, coords, wpwH, wdwS, bias2, bpw, out);
}

// Round 7
// 436.549 us; speedup vs baseline: 1.1625x; 1.1625x over previous
//
#include <hip/hip_runtime.h>
#include <math.h>

typedef _Float16 f16x8 __attribute__((ext_vector_type(8)));
typedef _Float16 f16x2 __attribute__((ext_vector_type(2)));
typedef float f32x4 __attribute__((ext_vector_type(4)));

namespace {
constexpr int B_ = 16, C_ = 128, H_ = 96, W_ = 96;
constexpr int HW_ = H_ * W_;
constexpr int G_ = 4, S_ = 2;
constexpr int CO_ = 32;        // offset channels
constexpr int COUT_ = 64;
constexpr int HO_ = 192, WO_ = 192;
constexpr int CPG_ = C_ / G_;  // 32 channels per sampling group
constexpr int TH_ = 8, TW_ = 32;   // 32-wide => full 128B out lines per block
constexpr int HALO_H = TH_ + 2, HALO_W = TW_ + 2;
constexpr int NPOS = HALO_H * HALO_W;   // 340
constexpr int UPS_F = 34;    // up row stride (f16): word-stride 17 -> conflict-free
constexpr int UP_BYTES = NPOS * UPS_F * 2;         // 23120
constexpr int Y8_BYTES = 256 * 8 * 2;              // 4096 (8 ch/quarter, 16B rows)
constexpr int POOL_BYTES = UP_BYTES + Y8_BYTES;    // 27216 (>= 16*257*4 clds overlay)

// ws float offsets
constexpr size_t WS_OFF1   = 0;                                   // [B,32,96,96]
constexpr size_t WS_COORDS = (size_t)B_ * CO_ * HW_;              // [B,G,HO,WO,2]
constexpr size_t WS_WPWH   = WS_COORDS + (size_t)B_ * G_ * HO_ * WO_ * 2;  // f16[8192]
constexpr size_t WS_WO1T   = WS_WPWH + (C_ * COUT_) / 2;          // f32[128*32]
constexpr size_t WS_WO2T   = WS_WO1T + C_ * CO_;                  // f32[288*32]
constexpr size_t WS_WDWS   = WS_WO2T + CO_ * 9 * CO_;             // f32[9*128]
constexpr size_t WS_BIAS2  = WS_WDWS + 9 * C_;                    // f32[128]

constexpr int PREP_N = C_ * COUT_ + C_ * CO_ + CO_ * CO_ * 9 + 9 * C_ + C_;
}

// --- Kernel P: Wpw->fp16; Wo1/Wo2 transposes; BN-folded dw weights + bias ---
__global__ __launch_bounds__(256) void k_prep(
    const float* __restrict__ Wpw, const float* __restrict__ Wo1,
    const float* __restrict__ Wo2, const float* __restrict__ Wdw,
    const float* __restrict__ bn_gamma, const float* __restrict__ bn_beta,
    const float* __restrict__ bn_mean, const float* __restrict__ bn_var,
    _Float16* __restrict__ wpwH, float* __restrict__ wo1T,
    float* __restrict__ wo2T, float* __restrict__ wdwS,
    float* __restrict__ bias2) {
  int i = blockIdx.x * 256 + threadIdx.x;
  if (i < C_ * COUT_) {
    wpwH[i] = (_Float16)Wpw[i];
  } else if (i < C_ * COUT_ + C_ * CO_) {
    int j = i - C_ * COUT_;
    int o = j >> 7, c = j & 127;   // Wo1 is [32][128]
    wo1T[c * CO_ + o] = Wo1[j];
  } else if (i < C_ * COUT_ + C_ * CO_ + CO_ * CO_ * 9) {
    int j = i - C_ * COUT_ - C_ * CO_;  // Wo2 is [32][288]
    int o = j / 288, r = j % 288;
    wo2T[r * CO_ + o] = Wo2[j];
  } else if (i < C_ * COUT_ + C_ * CO_ + CO_ * CO_ * 9 + 9 * C_) {
    int j = i - C_ * COUT_ - C_ * CO_ - CO_ * CO_ * 9;  // Wdw is [c][9]
    int c = j / 9, t = j % 9;
    float sc = bn_gamma[c] * rsqrtf(bn_var[c] + 1e-5f);
    wdwS[t * C_ + c] = Wdw[j] * sc;
  } else if (i < PREP_N) {
    int c = i - (C_ * COUT_ + C_ * CO_ + CO_ * CO_ * 9 + 9 * C_);
    float sc = bn_gamma[c] * rsqrtf(bn_var[c] + 1e-5f);
    bias2[c] = bn_beta[c] - bn_mean[c] * sc;
  }
}

// ------- Kernel A: 1x1 conv (128 -> 32) + bias, 1 px/thread --------
__global__ __launch_bounds__(256) void k_off1(const float* __restrict__ x,
                                              const float* __restrict__ wo1T,
                                              const float* __restrict__ bo1,
                                              float* __restrict__ off1) {
  int p = blockIdx.x * 256 + threadIdx.x;  // B*HW threads
  int b = p / HW_, hw = p % HW_;
  float acc[CO_];
#pragma unroll
  for (int o = 0; o < CO_; ++o) acc[o] = bo1[o];  // uniform -> s_load
  const float* xb = x + (size_t)b * C_ * HW_ + hw;
  for (int c = 0; c < C_; ++c) {
    float xv = xb[c * HW_];
    const float* wr = wo1T + c * CO_;  // uniform rows -> s_load
#pragma unroll
    for (int o = 0; o < CO_; ++o) acc[o] = fmaf(xv, wr[o], acc[o]);
  }
  float* ob = off1 + (size_t)b * CO_ * HW_ + hw;
#pragma unroll
  for (int o = 0; o < CO_; ++o) ob[o * HW_] = acc[o];
}

// -- Kernel B: 3x3 dil(2) conv (32->32) -> sample coords, 1 px/thread --
__global__ __launch_bounds__(256) void k_coords(const float* __restrict__ off1,
                                                const float* __restrict__ wo2T,
                                                float* __restrict__ coords) {
  int p = blockIdx.x * 256 + threadIdx.x;
  int b = p / HW_, hw = p % HW_;
  int h = hw / W_, w = hw % W_;
  float acc[CO_];
#pragma unroll
  for (int o = 0; o < CO_; ++o) acc[o] = 0.f;
  const float* ib = off1 + (size_t)b * CO_ * HW_;
#pragma unroll
  for (int ky = 0; ky < 3; ++ky) {
    int hh = h + 2 * (ky - 1);
    if ((unsigned)hh < (unsigned)H_) {
      const float* rbase = ib + hh * W_ + w;
      for (int ci = 0; ci < CO_; ++ci) {
        const float* rp = rbase + ci * HW_;
        float vL = (w >= 2) ? rp[-2] : 0.f;
        float vM = rp[0];
        float vR = (w < W_ - 2) ? rp[2] : 0.f;
        const float* wr = wo2T + (ci * 9 + ky * 3) * CO_;  // uniform -> s_load
#pragma unroll
        for (int o = 0; o < CO_; ++o)
          acc[o] = fmaf(vL, wr[o],
                   fmaf(vM, wr[CO_ + o], fmaf(vR, wr[2 * CO_ + o], acc[o])));
      }
    }
  }
  float cwv = (float)w + sinf((float)M_PI * (float)(w + 1) / (float)W_);
  float chv = (float)h + sinf((float)M_PI * (float)(h + 1) / (float)H_);
  float* cb = coords + (size_t)b * G_ * HO_ * WO_ * 2;
#pragma unroll
  for (int g = 0; g < G_; ++g) {
#pragma unroll
    for (int sh = 0; sh < S_; ++sh) {
#pragma unroll
      for (int sw = 0; sw < S_; ++sw) {
        int idx = g * 4 + sh * 2 + sw;
        float offx = acc[idx] * 0.25f + (sw ? 0.25f : -0.25f);
        float offy = acc[16 + idx] * 0.25f + (sh ? 0.25f : -0.25f);
        float ix = fminf(fmaxf(cwv + offx - 0.5f, 0.f), (float)(W_ - 1));
        float iy = fminf(fmaxf(chv + offy - 0.5f, 0.f), (float)(H_ - 1));
        float2* dst = (float2*)(cb + (((size_t)g * HO_ + 2 * h + sh) * WO_
                                      + 2 * w + sw) * 2);
        *dst = (float2){ix, iy};
      }
    }
  }
}

// -- Kernel C: grid_sample (f16 LDS) + dw3x3+BN+ReLU (4 quarter-passes) + MFMA --
// 32x8 output tiles: every wave writes full 128B lines, no inter-block line
// sharing. XCD-contiguous swizzle keeps each XCD on 2 whole images.
__global__ __launch_bounds__(256, 5) void k_fused(
    const float* __restrict__ x, const float* __restrict__ coords,
    const _Float16* __restrict__ wpwH, const float* __restrict__ wdwS,
    const float* __restrict__ bias2, const float* __restrict__ bpw,
    float* __restrict__ out) {
  __shared__ __align__(16) unsigned char pool[POOL_BYTES];  // up + ylds8 / clds16
  _Float16 (*up)[UPS_F] = (_Float16(*)[UPS_F])pool;
  _Float16* ylds8 = (_Float16*)(pool + UP_BYTES);  // [256][8], 16 B rows

  constexpr int TILES_W = WO_ / TW_;            // 6
  constexpr int TILES = TILES_W * (HO_ / TH_);  // 144
  constexpr int NWG = B_ * TILES;               // 2304 (% 8 == 0)
  // bijective XCD-contiguous swizzle: XCD k gets original blocks [k*288,(k+1)*288)
  int bid = blockIdx.x;
  int swz = (bid & 7) * (NWG / 8) + (bid >> 3);
  int b = swz / TILES;
  int t = swz % TILES;
  int oh0 = (t / TILES_W) * TH_;
  int ow0 = (t % TILES_W) * TW_;
  int tid = threadIdx.x;
  int py = tid >> 5, px = tid & 31;  // 8 x 32 tile
  int lane = tid & 63, wv_ = tid >> 6;
  int lr = lane & 15, lk = lane >> 4;

  f32x4 acc[4][4];
#pragma unroll
  for (int mt = 0; mt < 4; ++mt)
#pragma unroll
    for (int nt = 0; nt < 4; ++nt) acc[mt][nt] = (f32x4){0.f, 0.f, 0.f, 0.f};

  for (int g = 0; g < G_; ++g) {
    __syncthreads();  // protects `up` reuse across g
    const float* xg = x + ((size_t)b * C_ + g * CPG_) * HW_;
    const float* cbase = coords + (((size_t)b * G_ + g) * HO_ * WO_) * 2;
    // ---- sampling: work item = (halo position, channel-octet) ----
    for (int wi = tid; wi < NPOS * 4; wi += 256) {
      int p = wi >> 2, cq = wi & 3;
      int hy = oh0 + p / HALO_W - 1;
      int hx = ow0 + p % HALO_W - 1;
      _Float16* dst = &up[p][cq * 8];
      if (hy < 0 || hy >= HO_ || hx < 0 || hx >= WO_) {
#pragma unroll
        for (int j2 = 0; j2 < 4; ++j2)
          *(f16x2*)&dst[2 * j2] = (f16x2){(_Float16)0.f, (_Float16)0.f};
      } else {
        float2 c2 = *(const float2*)&cbase[((size_t)hy * WO_ + hx) * 2];
        float ix = c2.x, iy = c2.y;
        float x0f = floorf(ix), y0f = floorf(iy);
        float wx = ix - x0f, wy = iy - y0f;
        int x0 = (int)x0f, y0 = (int)y0f;  // already in [0, 95]
        int x1 = min(x0 + 1, W_ - 1);
        int y1 = min(y0 + 1, H_ - 1);
        float w00 = (1.f - wx) * (1.f - wy);
        float w01 = wx * (1.f - wy);
        float w10 = (1.f - wx) * wy;
        float w11 = wx * wy;
        const float* r0 = xg + (size_t)(cq * 8) * HW_ + y0 * W_;
        const float* r1 = xg + (size_t)(cq * 8) * HW_ + y1 * W_;
#pragma unroll
        for (int j2 = 0; j2 < 4; ++j2) {
          int offA = (2 * j2) * HW_, offB = offA + HW_;
          float v0 = w00 * r0[offA + x0] + w01 * r0[offA + x1] +
                     w10 * r1[offA + x0] + w11 * r1[offA + x1];
          float v1 = w00 * r0[offB + x0] + w01 * r0[offB + x1] +
                     w10 * r1[offB + x0] + w11 * r1[offB + x1];
          *(f16x2*)&dst[2 * j2] = (f16x2){(_Float16)v0, (_Float16)v1};
        }
      }
    }
    __syncthreads();

    // ---- dw3x3+BN+ReLU in four 8-channel quarter-passes ----
    f16x8 afr[4];
#pragma unroll
    for (int q = 0; q < 4; ++q) {
      if (q) __syncthreads();  // ylds8 overwrite after prev quarter frag loads
      f16x2 yreg[4];
#pragma unroll
      for (int cp = 0; cp < 4; ++cp) {
        int cl = 2 * cp;                     // channel within quarter
        int c = g * CPG_ + q * 8 + cl;       // global channel (loop-uniform)
        float2 bi = *(const float2*)&bias2[c];        // s_load
        float dw0 = bi.x, dw1 = bi.y;
#pragma unroll
        for (int tt = 0; tt < 9; ++tt) {
          int dy = tt / 3, dx = tt % 3;
          f16x2 pk = *(const f16x2*)&up[(py + dy) * HALO_W + px + dx][q * 8 + cl];
          float2 wv = *(const float2*)&wdwS[tt * C_ + c];  // s_load
          dw0 = fmaf((float)pk.x, wv.x, dw0);
          dw1 = fmaf((float)pk.y, wv.y, dw1);
        }
        yreg[cp] = (f16x2){(_Float16)fmaxf(dw0, 0.f), (_Float16)fmaxf(dw1, 0.f)};
      }
      f16x8 yv;
#pragma unroll
      for (int cp = 0; cp < 4; ++cp) { yv[2 * cp] = yreg[cp].x; yv[2 * cp + 1] = yreg[cp].y; }
      *(f16x8*)&ylds8[tid * 8] = yv;   // one ds_write_b128, contiguous
      __syncthreads();
      if (lk == q) {  // this lane's k-slot lives in this quarter
#pragma unroll
        for (int mt = 0; mt < 4; ++mt)
          afr[mt] = *(const f16x8*)&ylds8[((wv_ * 4 + mt) * 16 + lr) * 8];
      }
    }
    // ---- one K=32 MFMA set per g ----
#pragma unroll
    for (int nt = 0; nt < 4; ++nt) {
      f16x8 bfr = *(const f16x8*)&wpwH[(nt * 16 + lr) * C_ + g * CPG_ + lk * 8];
#pragma unroll
      for (int mt = 0; mt < 4; ++mt)
        acc[mt][nt] = __builtin_amdgcn_mfma_f32_16x16x32_f16(afr[mt], bfr,
                                                             acc[mt][nt], 0, 0, 0);
    }
  }

  // ---- epilogue: 4 rounds of 16 channels via clds16 overlay ----
  float (*clds16)[257] = (float(*)[257])pool;  // [16][257] = 16448 B
  int oh = oh0 + py, ow = ow0 + px;
#pragma unroll
  for (int hq = 0; hq < 4; ++hq) {
    __syncthreads();  // first iter: all waves done with up/ylds8
#pragma unroll
    for (int mt = 0; mt < 4; ++mt) {
#pragma unroll
      for (int r = 0; r < 4; ++r)
        clds16[lr][(wv_ * 4 + mt) * 16 + lk * 4 + r] = acc[mt][hq][r];
    }
    __syncthreads();
#pragma unroll
    for (int i = 0; i < 16; ++i) {
      int o = hq * 16 + i;
      out[(((size_t)b * COUT_ + o) * HO_ + oh) * WO_ + ow] = clds16[i][tid] + bpw[o];
    }
  }
}

extern "C" void kernel_launch(void* const* d_in, const int* in_sizes, int n_in,
                              void* d_out, int out_size, void* d_ws, size_t ws_size,
                              hipStream_t stream) {
  const float* x        = (const float*)d_in[0];
  const float* Wo1      = (const float*)d_in[1];
  const float* bo1      = (const float*)d_in[2];
  const float* Wo2      = (const float*)d_in[3];
  const float* Wdw      = (const float*)d_in[4];
  const float* bn_gamma = (const float*)d_in[5];
  const float* bn_beta  = (const float*)d_in[6];
  const float* bn_mean  = (const float*)d_in[7];
  const float* bn_var   = (const float*)d_in[8];
  const float* Wpw      = (const float*)d_in[9];
  const float* bpw      = (const float*)d_in[10];
  float* out = (float*)d_out;

  float* ws = (float*)d_ws;
  float* off1        = ws + WS_OFF1;
  float* coords      = ws + WS_COORDS;
  _Float16* wpwH     = (_Float16*)(ws + WS_WPWH);
  float* wo1T        = ws + WS_WO1T;
  float* wo2T        = ws + WS_WO2T;
  float* wdwS        = ws + WS_WDWS;
  float* bias2       = ws + WS_BIAS2;

  k_prep  <<<(PREP_N + 255) / 256, 256, 0, stream>>>(
      Wpw, Wo1, Wo2, Wdw, bn_gamma, bn_beta, bn_mean, bn_var,
      wpwH, wo1T, wo2T, wdwS, bias2);
  k_off1  <<<(B_ * HW_) / 256, 256, 0, stream>>>(x, wo1T, bo1, off1);
  k_coords<<<(B_ * HW_) / 256, 256, 0, stream>>>(off1, wo2T, coords);
  k_fused <<<B_ * 144, 256, 0, stream>>>(x, coords, wpwH, wdwS, bias2, bpw, out);
}

// Round 8
// 396.230 us; speedup vs baseline: 1.2808x; 1.1018x over previous
//
#include <hip/hip_runtime.h>
#include <math.h>

typedef _Float16 f16x8 __attribute__((ext_vector_type(8)));
typedef _Float16 f16x2 __attribute__((ext_vector_type(2)));
typedef float f32x4 __attribute__((ext_vector_type(4)));

namespace {
constexpr int B_ = 16, C_ = 128, H_ = 96, W_ = 96;
constexpr int HW_ = H_ * W_;
constexpr int G_ = 4, S_ = 2;
constexpr int CO_ = 32;        // offset channels
constexpr int COUT_ = 64;
constexpr int HO_ = 192, WO_ = 192;
constexpr int CPG_ = C_ / G_;  // 32 channels per sampling group
constexpr int TH_ = 8, TW_ = 32;   // 32-wide => full 128B out lines per block
constexpr int HALO_H = TH_ + 2, HALO_W = TW_ + 2;
constexpr int NPOS = HALO_H * HALO_W;   // 340
constexpr int UPS_F = 34;    // up row stride (f16): word-stride 17 -> conflict-free
constexpr int YROW16 = 24;   // ylds16 row stride (f16): 48 B
constexpr int UP_BYTES = NPOS * UPS_F * 2;         // 23120
constexpr int Y16_BYTES = 256 * YROW16 * 2;        // 12288
constexpr int POOL_BYTES = UP_BYTES + Y16_BYTES;   // 35408 (>= 16*257*4 clds overlay)

// ws float offsets
constexpr size_t WS_OFF1   = 0;                                   // [B,32,96,96]
constexpr size_t WS_COORDS = (size_t)B_ * CO_ * HW_;              // [B,G,HO,WO,2]
constexpr size_t WS_WPWH   = WS_COORDS + (size_t)B_ * G_ * HO_ * WO_ * 2;  // f16[8192]
constexpr size_t WS_WO1T   = WS_WPWH + (C_ * COUT_) / 2;          // f32[128*32]
constexpr size_t WS_WO2T   = WS_WO1T + C_ * CO_;                  // f32[288*32]
constexpr size_t WS_WDWS   = WS_WO2T + CO_ * 9 * CO_;             // f32[9*128]
constexpr size_t WS_BIAS2  = WS_WDWS + 9 * C_;                    // f32[128]

constexpr int PREP_N = C_ * COUT_ + C_ * CO_ + CO_ * CO_ * 9 + 9 * C_ + C_;
}

// --- Kernel P: Wpw->fp16; Wo1/Wo2 transposes; BN-folded dw weights + bias ---
__global__ __launch_bounds__(256) void k_prep(
    const float* __restrict__ Wpw, const float* __restrict__ Wo1,
    const float* __restrict__ Wo2, const float* __restrict__ Wdw,
    const float* __restrict__ bn_gamma, const float* __restrict__ bn_beta,
    const float* __restrict__ bn_mean, const float* __restrict__ bn_var,
    _Float16* __restrict__ wpwH, float* __restrict__ wo1T,
    float* __restrict__ wo2T, float* __restrict__ wdwS,
    float* __restrict__ bias2) {
  int i = blockIdx.x * 256 + threadIdx.x;
  if (i < C_ * COUT_) {
    wpwH[i] = (_Float16)Wpw[i];
  } else if (i < C_ * COUT_ + C_ * CO_) {
    int j = i - C_ * COUT_;
    int o = j >> 7, c = j & 127;   // Wo1 is [32][128]
    wo1T[c * CO_ + o] = Wo1[j];
  } else if (i < C_ * COUT_ + C_ * CO_ + CO_ * CO_ * 9) {
    int j = i - C_ * COUT_ - C_ * CO_;  // Wo2 is [32][288]
    int o = j / 288, r = j % 288;
    wo2T[r * CO_ + o] = Wo2[j];
  } else if (i < C_ * COUT_ + C_ * CO_ + CO_ * CO_ * 9 + 9 * C_) {
    int j = i - C_ * COUT_ - C_ * CO_ - CO_ * CO_ * 9;  // Wdw is [c][9]
    int c = j / 9, t = j % 9;
    float sc = bn_gamma[c] * rsqrtf(bn_var[c] + 1e-5f);
    wdwS[t * C_ + c] = Wdw[j] * sc;
  } else if (i < PREP_N) {
    int c = i - (C_ * COUT_ + C_ * CO_ + CO_ * CO_ * 9 + 9 * C_);
    float sc = bn_gamma[c] * rsqrtf(bn_var[c] + 1e-5f);
    bias2[c] = bn_beta[c] - bn_mean[c] * sc;
  }
}

// ------- Kernel A: 1x1 conv (128 -> 32) + bias, 1 px/thread --------
__global__ __launch_bounds__(256) void k_off1(const float* __restrict__ x,
                                              const float* __restrict__ wo1T,
                                              const float* __restrict__ bo1,
                                              float* __restrict__ off1) {
  int p = blockIdx.x * 256 + threadIdx.x;  // B*HW threads
  int b = p / HW_, hw = p % HW_;
  float acc[CO_];
#pragma unroll
  for (int o = 0; o < CO_; ++o) acc[o] = bo1[o];  // uniform -> s_load
  const float* xb = x + (size_t)b * C_ * HW_ + hw;
  for (int c = 0; c < C_; ++c) {
    float xv = xb[c * HW_];
    const float* wr = wo1T + c * CO_;  // uniform rows -> s_load
#pragma unroll
    for (int o = 0; o < CO_; ++o) acc[o] = fmaf(xv, wr[o], acc[o]);
  }
  float* ob = off1 + (size_t)b * CO_ * HW_ + hw;
#pragma unroll
  for (int o = 0; o < CO_; ++o) ob[o * HW_] = acc[o];
}

// -- Kernel B: 3x3 dil(2) conv (32->32) -> sample coords, 1 px/thread --
__global__ __launch_bounds__(256) void k_coords(const float* __restrict__ off1,
                                                const float* __restrict__ wo2T,
                                                float* __restrict__ coords) {
  int p = blockIdx.x * 256 + threadIdx.x;
  int b = p / HW_, hw = p % HW_;
  int h = hw / W_, w = hw % W_;
  float acc[CO_];
#pragma unroll
  for (int o = 0; o < CO_; ++o) acc[o] = 0.f;
  const float* ib = off1 + (size_t)b * CO_ * HW_;
#pragma unroll
  for (int ky = 0; ky < 3; ++ky) {
    int hh = h + 2 * (ky - 1);
    if ((unsigned)hh < (unsigned)H_) {
      const float* rbase = ib + hh * W_ + w;
      for (int ci = 0; ci < CO_; ++ci) {
        const float* rp = rbase + ci * HW_;
        float vL = (w >= 2) ? rp[-2] : 0.f;
        float vM = rp[0];
        float vR = (w < W_ - 2) ? rp[2] : 0.f;
        const float* wr = wo2T + (ci * 9 + ky * 3) * CO_;  // uniform -> s_load
#pragma unroll
        for (int o = 0; o < CO_; ++o)
          acc[o] = fmaf(vL, wr[o],
                   fmaf(vM, wr[CO_ + o], fmaf(vR, wr[2 * CO_ + o], acc[o])));
      }
    }
  }
  float cwv = (float)w + sinf((float)M_PI * (float)(w + 1) / (float)W_);
  float chv = (float)h + sinf((float)M_PI * (float)(h + 1) / (float)H_);
  float* cb = coords + (size_t)b * G_ * HO_ * WO_ * 2;
#pragma unroll
  for (int g = 0; g < G_; ++g) {
#pragma unroll
    for (int sh = 0; sh < S_; ++sh) {
#pragma unroll
      for (int sw = 0; sw < S_; ++sw) {
        int idx = g * 4 + sh * 2 + sw;
        float offx = acc[idx] * 0.25f + (sw ? 0.25f : -0.25f);
        float offy = acc[16 + idx] * 0.25f + (sh ? 0.25f : -0.25f);
        float ix = fminf(fmaxf(cwv + offx - 0.5f, 0.f), (float)(W_ - 1));
        float iy = fminf(fmaxf(chv + offy - 0.5f, 0.f), (float)(H_ - 1));
        float2* dst = (float2*)(cb + (((size_t)g * HO_ + 2 * h + sh) * WO_
                                      + 2 * w + sw) * 2);
        *dst = (float2){ix, iy};
      }
    }
  }
}

// -- Kernel C: grid_sample (f16 LDS) + dw3x3+BN+ReLU (2 half-passes) + MFMA --
// Round-5 structure (16-ch half-passes, 4 blocks/CU) + 32x8 full-line tiles
// + bijective XCD-contiguous swizzle. Weight tables via wave-uniform s_loads.
__global__ __launch_bounds__(256, 4) void k_fused(
    const float* __restrict__ x, const float* __restrict__ coords,
    const _Float16* __restrict__ wpwH, const float* __restrict__ wdwS,
    const float* __restrict__ bias2, const float* __restrict__ bpw,
    float* __restrict__ out) {
  __shared__ __align__(16) unsigned char pool[POOL_BYTES];  // up + ylds16 / clds16
  _Float16 (*up)[UPS_F] = (_Float16(*)[UPS_F])pool;
  _Float16 (*ylds16)[YROW16] = (_Float16(*)[YROW16])(pool + UP_BYTES);

  constexpr int TILES_W = WO_ / TW_;            // 6
  constexpr int TILES = TILES_W * (HO_ / TH_);  // 144
  constexpr int NWG = B_ * TILES;               // 2304 (% 8 == 0)
  // bijective XCD-contiguous swizzle: XCD k gets original blocks [k*288,(k+1)*288)
  int bid = blockIdx.x;
  int swz = (bid & 7) * (NWG / 8) + (bid >> 3);
  int b = swz / TILES;
  int t = swz % TILES;
  int oh0 = (t / TILES_W) * TH_;
  int ow0 = (t % TILES_W) * TW_;
  int tid = threadIdx.x;
  int py = tid >> 5, px = tid & 31;  // 8 x 32 tile
  int lane = tid & 63, wv_ = tid >> 6;
  int lr = lane & 15, lk = lane >> 4;

  f32x4 acc[4][4];
#pragma unroll
  for (int mt = 0; mt < 4; ++mt)
#pragma unroll
    for (int nt = 0; nt < 4; ++nt) acc[mt][nt] = (f32x4){0.f, 0.f, 0.f, 0.f};

  for (int g = 0; g < G_; ++g) {
    __syncthreads();  // protects `up` reuse across g
    const float* xg = x + ((size_t)b * C_ + g * CPG_) * HW_;
    const float* cbase = coords + (((size_t)b * G_ + g) * HO_ * WO_) * 2;
    // ---- sampling: work item = (halo position, channel-octet) ----
    for (int wi = tid; wi < NPOS * 4; wi += 256) {
      int p = wi >> 2, cq = wi & 3;
      int hy = oh0 + p / HALO_W - 1;
      int hx = ow0 + p % HALO_W - 1;
      _Float16* dst = &up[p][cq * 8];
      if (hy < 0 || hy >= HO_ || hx < 0 || hx >= WO_) {
#pragma unroll
        for (int j2 = 0; j2 < 4; ++j2)
          *(f16x2*)&dst[2 * j2] = (f16x2){(_Float16)0.f, (_Float16)0.f};
      } else {
        float2 c2 = *(const float2*)&cbase[((size_t)hy * WO_ + hx) * 2];
        float ix = c2.x, iy = c2.y;
        float x0f = floorf(ix), y0f = floorf(iy);
        float wx = ix - x0f, wy = iy - y0f;
        int x0 = (int)x0f, y0 = (int)y0f;  // already in [0, 95]
        int x1 = min(x0 + 1, W_ - 1);
        int y1 = min(y0 + 1, H_ - 1);
        float w00 = (1.f - wx) * (1.f - wy);
        float w01 = wx * (1.f - wy);
        float w10 = (1.f - wx) * wy;
        float w11 = wx * wy;
        const float* r0 = xg + (size_t)(cq * 8) * HW_ + y0 * W_;
        const float* r1 = xg + (size_t)(cq * 8) * HW_ + y1 * W_;
#pragma unroll
        for (int j2 = 0; j2 < 4; ++j2) {
          int offA = (2 * j2) * HW_, offB = offA + HW_;
          float v0 = w00 * r0[offA + x0] + w01 * r0[offA + x1] +
                     w10 * r1[offA + x0] + w11 * r1[offA + x1];
          float v1 = w00 * r0[offB + x0] + w01 * r0[offB + x1] +
                     w10 * r1[offB + x0] + w11 * r1[offB + x1];
          *(f16x2*)&dst[2 * j2] = (f16x2){(_Float16)v0, (_Float16)v1};
        }
      }
    }
    __syncthreads();

    // ---- dw3x3+BN+ReLU in two 16-channel half-passes; A-frags by lane half ----
    f16x8 afr[4];
#pragma unroll
    for (int half = 0; half < 2; ++half) {
      if (half) __syncthreads();  // ylds16 overwrite after half-0 frag loads
#pragma unroll
      for (int cp = 0; cp < 8; ++cp) {
        int cl = 2 * cp;                       // channel-in-half
        int c = g * CPG_ + half * 16 + cl;     // global channel (loop-uniform)
        float2 bi = *(const float2*)&bias2[c];          // s_load
        float dw0 = bi.x, dw1 = bi.y;
#pragma unroll
        for (int tt = 0; tt < 9; ++tt) {
          int dy = tt / 3, dx = tt % 3;
          f16x2 pk = *(const f16x2*)&up[(py + dy) * HALO_W + px + dx][half * 16 + cl];
          float2 wv = *(const float2*)&wdwS[tt * C_ + c];  // s_load
          dw0 = fmaf((float)pk.x, wv.x, dw0);
          dw1 = fmaf((float)pk.y, wv.y, dw1);
        }
        *(f16x2*)&ylds16[tid][cl] =
            (f16x2){(_Float16)fmaxf(dw0, 0.f), (_Float16)fmaxf(dw1, 0.f)};
      }
      __syncthreads();
      if ((lk >> 1) == half) {  // this lane's k-slot lives in this half
#pragma unroll
        for (int mt = 0; mt < 4; ++mt)
          afr[mt] = *(const f16x8*)&ylds16[(wv_ * 4 + mt) * 16 + lr][(lk & 1) * 8];
      }
    }
    // ---- one K=32 MFMA set per g ----
#pragma unroll
    for (int nt = 0; nt < 4; ++nt) {
      f16x8 bfr = *(const f16x8*)&wpwH[(nt * 16 + lr) * C_ + g * CPG_ + lk * 8];
#pragma unroll
      for (int mt = 0; mt < 4; ++mt)
        acc[mt][nt] = __builtin_amdgcn_mfma_f32_16x16x32_f16(afr[mt], bfr,
                                                             acc[mt][nt], 0, 0, 0);
    }
  }

  // ---- epilogue: 4 rounds of 16 channels via clds16 overlay ----
  float (*clds16)[257] = (float(*)[257])pool;  // [16][257] = 16448 B
  int oh = oh0 + py, ow = ow0 + px;
#pragma unroll
  for (int hq = 0; hq < 4; ++hq) {
    __syncthreads();  // first iter: all waves done with up/ylds16
#pragma unroll
    for (int mt = 0; mt < 4; ++mt) {
#pragma unroll
      for (int r = 0; r < 4; ++r)
        clds16[lr][(wv_ * 4 + mt) * 16 + lk * 4 + r] = acc[mt][hq][r];
    }
    __syncthreads();
#pragma unroll
    for (int i = 0; i < 16; ++i) {
      int o = hq * 16 + i;
      out[(((size_t)b * COUT_ + o) * HO_ + oh) * WO_ + ow] = clds16[i][tid] + bpw[o];
    }
  }
}

extern "C" void kernel_launch(void* const* d_in, const int* in_sizes, int n_in,
                              void* d_out, int out_size, void* d_ws, size_t ws_size,
                              hipStream_t stream) {
  const float* x        = (const float*)d_in[0];
  const float* Wo1      = (const float*)d_in[1];
  const float* bo1      = (const float*)d_in[2];
  const float* Wo2      = (const float*)d_in[3];
  const float* Wdw      = (const float*)d_in[4];
  const float* bn_gamma = (const float*)d_in[5];
  const float* bn_beta  = (const float*)d_in[6];
  const float* bn_mean  = (const float*)d_in[7];
  const float* bn_var   = (const float*)d_in[8];
  const float* Wpw      = (const float*)d_in[9];
  const float* bpw      = (const float*)d_in[10];
  float* out = (float*)d_out;

  float* ws = (float*)d_ws;
  float* off1        = ws + WS_OFF1;
  float* coords      = ws + WS_COORDS;
  _Float16* wpwH     = (_Float16*)(ws + WS_WPWH);
  float* wo1T        = ws + WS_WO1T;
  float* wo2T        = ws + WS_WO2T;
  float* wdwS        = ws + WS_WDWS;
  float* bias2       = ws + WS_BIAS2;

  k_prep  <<<(PREP_N + 255) / 256, 256, 0, stream>>>(
      Wpw, Wo1, Wo2, Wdw, bn_gamma, bn_beta, bn_mean, bn_var,
      wpwH, wo1T, wo2T, wdwS, bias2);
  k_off1  <<<(B_ * HW_) / 256, 256, 0, stream>>>(x, wo1T, bo1, off1);
  k_coords<<<(B_ * HW_) / 256, 256, 0, stream>>>(off1, wo2T, coords);
  k_fused <<<B_ * 144, 256, 0, stream>>>(x, coords, wpwH, wdwS, bias2, bpw, out);
}

// Round 9
// 388.151 us; speedup vs baseline: 1.3074x; 1.0208x over previous
//
#include <hip/hip_runtime.h>
#include <math.h>

typedef _Float16 f16x8 __attribute__((ext_vector_type(8)));
typedef _Float16 f16x2 __attribute__((ext_vector_type(2)));
typedef float f32x4 __attribute__((ext_vector_type(4)));

namespace {
constexpr int B_ = 16, C_ = 128, H_ = 96, W_ = 96;
constexpr int HW_ = H_ * W_;
constexpr int G_ = 4, S_ = 2;
constexpr int CO_ = 32;        // offset channels
constexpr int COUT_ = 64;
constexpr int HO_ = 192, WO_ = 192;
constexpr int HWO_ = HO_ * WO_;   // 36864
constexpr int CPG_ = C_ / G_;  // 32 channels per sampling group
constexpr int TH_ = 8, TW_ = 32;   // 32-wide tiles
constexpr int HALO_H = TH_ + 2, HALO_W = TW_ + 2;
constexpr int NPOS = HALO_H * HALO_W;   // 340
constexpr int UPS_F = 34;    // up row stride (f16): word-stride 17 -> conflict-free
constexpr int TILES = (WO_ / TW_) * (HO_ / TH_);  // 144

// ws float offsets
constexpr size_t WS_OFF1   = 0;                                   // [B,32,96,96]
constexpr size_t WS_COORDS = (size_t)B_ * CO_ * HW_;              // 4718592
constexpr size_t WS_WPWH   = WS_COORDS + (size_t)B_ * G_ * HO_ * WO_ * 2;
constexpr size_t WS_WO1T   = WS_WPWH + (C_ * COUT_) / 2;
constexpr size_t WS_WO2T   = WS_WO1T + C_ * CO_;
constexpr size_t WS_WDWS   = WS_WO2T + CO_ * 9 * CO_;
constexpr size_t WS_BIAS2  = WS_WDWS + 9 * C_;
constexpr size_t WS_Y      = WS_BIAS2 + C_;                       // 9455872 floats
// y sizes (in float units): full 16-img = 37748736; 8-img = 18874368; 2-img = 4718592
constexpr size_t Y_FULL_F  = (size_t)B_ * G_ * HWO_ * CPG_ / 2;   // 37748736
constexpr size_t NEED_FULL = (WS_Y + Y_FULL_F) * 4;               // 188.8 MB
constexpr size_t NEED_MID  = (WS_Y + Y_FULL_F / 2) * 4;           // 113.3 MB

constexpr int PREP_N = C_ * COUT_ + C_ * CO_ + CO_ * CO_ * 9 + 9 * C_ + C_;
}

// --- Kernel P: Wpw->fp16; Wo1/Wo2 transposes; BN-folded dw weights + bias ---
__global__ __launch_bounds__(256) void k_prep(
    const float* __restrict__ Wpw, const float* __restrict__ Wo1,
    const float* __restrict__ Wo2, const float* __restrict__ Wdw,
    const float* __restrict__ bn_gamma, const float* __restrict__ bn_beta,
    const float* __restrict__ bn_mean, const float* __restrict__ bn_var,
    _Float16* __restrict__ wpwH, float* __restrict__ wo1T,
    float* __restrict__ wo2T, float* __restrict__ wdwS,
    float* __restrict__ bias2) {
  int i = blockIdx.x * 256 + threadIdx.x;
  if (i < C_ * COUT_) {
    wpwH[i] = (_Float16)Wpw[i];
  } else if (i < C_ * COUT_ + C_ * CO_) {
    int j = i - C_ * COUT_;
    int o = j >> 7, c = j & 127;   // Wo1 is [32][128]
    wo1T[c * CO_ + o] = Wo1[j];
  } else if (i < C_ * COUT_ + C_ * CO_ + CO_ * CO_ * 9) {
    int j = i - C_ * COUT_ - C_ * CO_;  // Wo2 is [32][288]
    int o = j / 288, r = j % 288;
    wo2T[r * CO_ + o] = Wo2[j];
  } else if (i < C_ * COUT_ + C_ * CO_ + CO_ * CO_ * 9 + 9 * C_) {
    int j = i - C_ * COUT_ - C_ * CO_ - CO_ * CO_ * 9;  // Wdw is [c][9]
    int c = j / 9, t = j % 9;
    float sc = bn_gamma[c] * rsqrtf(bn_var[c] + 1e-5f);
    wdwS[t * C_ + c] = Wdw[j] * sc;
  } else if (i < PREP_N) {
    int c = i - (C_ * COUT_ + C_ * CO_ + CO_ * CO_ * 9 + 9 * C_);
    float sc = bn_gamma[c] * rsqrtf(bn_var[c] + 1e-5f);
    bias2[c] = bn_beta[c] - bn_mean[c] * sc;
  }
}

// ------- Kernel A: 1x1 conv (128 -> 32) + bias, 1 px/thread --------
__global__ __launch_bounds__(256) void k_off1(const float* __restrict__ x,
                                              const float* __restrict__ wo1T,
                                              const float* __restrict__ bo1,
                                              float* __restrict__ off1) {
  int p = blockIdx.x * 256 + threadIdx.x;  // B*HW threads
  int b = p / HW_, hw = p % HW_;
  float acc[CO_];
#pragma unroll
  for (int o = 0; o < CO_; ++o) acc[o] = bo1[o];  // uniform -> s_load
  const float* xb = x + (size_t)b * C_ * HW_ + hw;
  for (int c = 0; c < C_; ++c) {
    float xv = xb[c * HW_];
    const float* wr = wo1T + c * CO_;  // uniform rows -> s_load
#pragma unroll
    for (int o = 0; o < CO_; ++o) acc[o] = fmaf(xv, wr[o], acc[o]);
  }
  float* ob = off1 + (size_t)b * CO_ * HW_ + hw;
#pragma unroll
  for (int o = 0; o < CO_; ++o) ob[o * HW_] = acc[o];
}

// -- Kernel B: 3x3 dil(2) conv (32->32) -> sample coords, 1 px/thread --
__global__ __launch_bounds__(256) void k_coords(const float* __restrict__ off1,
                                                const float* __restrict__ wo2T,
                                                float* __restrict__ coords) {
  int p = blockIdx.x * 256 + threadIdx.x;
  int b = p / HW_, hw = p % HW_;
  int h = hw / W_, w = hw % W_;
  float acc[CO_];
#pragma unroll
  for (int o = 0; o < CO_; ++o) acc[o] = 0.f;
  const float* ib = off1 + (size_t)b * CO_ * HW_;
#pragma unroll
  for (int ky = 0; ky < 3; ++ky) {
    int hh = h + 2 * (ky - 1);
    if ((unsigned)hh < (unsigned)H_) {
      const float* rbase = ib + hh * W_ + w;
      for (int ci = 0; ci < CO_; ++ci) {
        const float* rp = rbase + ci * HW_;
        float vL = (w >= 2) ? rp[-2] : 0.f;
        float vM = rp[0];
        float vR = (w < W_ - 2) ? rp[2] : 0.f;
        const float* wr = wo2T + (ci * 9 + ky * 3) * CO_;  // uniform -> s_load
#pragma unroll
        for (int o = 0; o < CO_; ++o)
          acc[o] = fmaf(vL, wr[o],
                   fmaf(vM, wr[CO_ + o], fmaf(vR, wr[2 * CO_ + o], acc[o])));
      }
    }
  }
  float cwv = (float)w + sinf((float)M_PI * (float)(w + 1) / (float)W_);
  float chv = (float)h + sinf((float)M_PI * (float)(h + 1) / (float)H_);
  float* cb = coords + (size_t)b * G_ * HO_ * WO_ * 2;
#pragma unroll
  for (int g = 0; g < G_; ++g) {
#pragma unroll
    for (int sh = 0; sh < S_; ++sh) {
#pragma unroll
      for (int sw = 0; sw < S_; ++sw) {
        int idx = g * 4 + sh * 2 + sw;
        float offx = acc[idx] * 0.25f + (sw ? 0.25f : -0.25f);
        float offy = acc[16 + idx] * 0.25f + (sh ? 0.25f : -0.25f);
        float ix = fminf(fmaxf(cwv + offx - 0.5f, 0.f), (float)(W_ - 1));
        float iy = fminf(fmaxf(chv + offy - 0.5f, 0.f), (float)(H_ - 1));
        float2* dst = (float2*)(cb + (((size_t)g * HO_ + 2 * h + sh) * WO_
                                      + 2 * w + sw) * 2);
        *dst = (float2){ix, iy};
      }
    }
  }
}

// -- Kernel S: grid_sample + dw3x3 + BN + ReLU -> y[b][g][pix][32] fp16 --
// Only `up` in LDS (23.1 KB) -> 6 blocks/CU. 9 barriers/block.
__global__ __launch_bounds__(256, 6) void k_sample(
    const float* __restrict__ x, const float* __restrict__ coords,
    const float* __restrict__ wdwS, const float* __restrict__ bias2,
    _Float16* __restrict__ y, int b0, int nimg) {
  __shared__ __align__(16) _Float16 up[NPOS][UPS_F];

  int NWG = nimg * TILES;
  int bid = blockIdx.x;
  int swz = (bid & 7) * (NWG >> 3) + (bid >> 3);  // NWG % 8 == 0 always
  int bl = swz / TILES;        // image within chunk
  int b = b0 + bl;
  int t = swz % TILES;
  int oh0 = (t / (WO_ / TW_)) * TH_;
  int ow0 = (t % (WO_ / TW_)) * TW_;
  int tid = threadIdx.x;
  int py = tid >> 5, px = tid & 31;  // 8 x 32 tile
  int p_out = (oh0 + py) * WO_ + ow0 + px;   // pixel id within image

  for (int g = 0; g < G_; ++g) {
    __syncthreads();  // protects `up` reuse across g
    const float* xg = x + ((size_t)b * C_ + g * CPG_) * HW_;
    const float* cbase = coords + (((size_t)b * G_ + g) * HO_ * WO_) * 2;
    // ---- sampling: work item = (halo position, channel-octet) ----
    for (int wi = tid; wi < NPOS * 4; wi += 256) {
      int p = wi >> 2, cq = wi & 3;
      int hy = oh0 + p / HALO_W - 1;
      int hx = ow0 + p % HALO_W - 1;
      _Float16* dst = &up[p][cq * 8];
      if (hy < 0 || hy >= HO_ || hx < 0 || hx >= WO_) {
#pragma unroll
        for (int j2 = 0; j2 < 4; ++j2)
          *(f16x2*)&dst[2 * j2] = (f16x2){(_Float16)0.f, (_Float16)0.f};
      } else {
        float2 c2 = *(const float2*)&cbase[((size_t)hy * WO_ + hx) * 2];
        float ix = c2.x, iy = c2.y;
        float x0f = floorf(ix), y0f = floorf(iy);
        float wx = ix - x0f, wy = iy - y0f;
        int x0 = (int)x0f, y0 = (int)y0f;  // already in [0, 95]
        int x1 = min(x0 + 1, W_ - 1);
        int y1 = min(y0 + 1, H_ - 1);
        float w00 = (1.f - wx) * (1.f - wy);
        float w01 = wx * (1.f - wy);
        float w10 = (1.f - wx) * wy;
        float w11 = wx * wy;
        const float* r0 = xg + (size_t)(cq * 8) * HW_ + y0 * W_;
        const float* r1 = xg + (size_t)(cq * 8) * HW_ + y1 * W_;
#pragma unroll
        for (int j2 = 0; j2 < 4; ++j2) {
          int offA = (2 * j2) * HW_, offB = offA + HW_;
          float v0 = w00 * r0[offA + x0] + w01 * r0[offA + x1] +
                     w10 * r1[offA + x0] + w11 * r1[offA + x1];
          float v1 = w00 * r0[offB + x0] + w01 * r0[offB + x1] +
                     w10 * r1[offB + x0] + w11 * r1[offB + x1];
          *(f16x2*)&dst[2 * j2] = (f16x2){(_Float16)v0, (_Float16)v1};
        }
      }
    }
    __syncthreads();

    // ---- dw3x3+BN+ReLU, 4 quarters of 8 channels -> y ----
    size_t ybase = ((size_t)(bl * G_ + g) * HWO_ + p_out) * (size_t)CPG_;
#pragma unroll
    for (int q = 0; q < 4; ++q) {
      f16x8 yv;
#pragma unroll
      for (int cp = 0; cp < 4; ++cp) {
        int cl = q * 8 + 2 * cp;           // channel within group
        int c = g * CPG_ + cl;             // global channel (loop-uniform)
        float2 bi = *(const float2*)&bias2[c];          // s_load
        float dw0 = bi.x, dw1 = bi.y;
#pragma unroll
        for (int tt = 0; tt < 9; ++tt) {
          int dy = tt / 3, dx = tt % 3;
          f16x2 pk = *(const f16x2*)&up[(py + dy) * HALO_W + px + dx][cl];
          float2 wv = *(const float2*)&wdwS[tt * C_ + c];  // s_load
          dw0 = fmaf((float)pk.x, wv.x, dw0);
          dw1 = fmaf((float)pk.y, wv.y, dw1);
        }
        yv[2 * cp] = (_Float16)fmaxf(dw0, 0.f);
        yv[2 * cp + 1] = (_Float16)fmaxf(dw1, 0.f);
      }
      *(f16x8*)&y[ybase + q * 8] = yv;   // 16B store, contiguous per thread
    }
  }
}

// -- Kernel G: streaming GEMM y[pix][128] @ W[128][64] -> out, MFMA --
__global__ __launch_bounds__(256, 4) void k_gemm(
    const _Float16* __restrict__ y, const _Float16* __restrict__ wpwH,
    const float* __restrict__ bpw, float* __restrict__ out, int b0, int nimg) {
  __shared__ float clds16[16][257];  // 16448 B

  int NWG = nimg * TILES;
  int bid = blockIdx.x;
  int swz = (bid & 7) * (NWG >> 3) + (bid >> 3);
  int bl = swz / TILES;
  int b = b0 + bl;
  int p0 = (swz % TILES) * 256;      // 144 * 256 = 36864 pixels per image
  int tid = threadIdx.x;
  int lane = tid & 63, wv_ = tid >> 6;
  int lr = lane & 15, lk = lane >> 4;

  f32x4 acc[4][4];
#pragma unroll
  for (int mt = 0; mt < 4; ++mt)
#pragma unroll
    for (int nt = 0; nt < 4; ++nt) acc[mt][nt] = (f32x4){0.f, 0.f, 0.f, 0.f};

  const _Float16* ybl = y + (size_t)bl * G_ * HWO_ * CPG_;
#pragma unroll
  for (int kk = 0; kk < 4; ++kk) {
    f16x8 afr[4];
#pragma unroll
    for (int mt = 0; mt < 4; ++mt)
      afr[mt] = *(const f16x8*)&ybl[((size_t)kk * HWO_ + p0 +
                                     (wv_ * 4 + mt) * 16 + lr) * CPG_ + lk * 8];
#pragma unroll
    for (int nt = 0; nt < 4; ++nt) {
      f16x8 bfr = *(const f16x8*)&wpwH[(nt * 16 + lr) * C_ + kk * CPG_ + lk * 8];
#pragma unroll
      for (int mt = 0; mt < 4; ++mt)
        acc[mt][nt] = __builtin_amdgcn_mfma_f32_16x16x32_f16(afr[mt], bfr,
                                                             acc[mt][nt], 0, 0, 0);
    }
  }

  // ---- epilogue: 4 rounds of 16 channels via clds16 transpose ----
#pragma unroll
  for (int hq = 0; hq < 4; ++hq) {
    if (hq) __syncthreads();
#pragma unroll
    for (int mt = 0; mt < 4; ++mt) {
#pragma unroll
      for (int r = 0; r < 4; ++r)
        clds16[lr][(wv_ * 4 + mt) * 16 + lk * 4 + r] = acc[mt][hq][r];
    }
    __syncthreads();
#pragma unroll
    for (int i = 0; i < 16; ++i) {
      int o = hq * 16 + i;
      out[((size_t)b * COUT_ + o) * HWO_ + p0 + tid] = clds16[i][tid] + bpw[o];
    }
  }
}

extern "C" void kernel_launch(void* const* d_in, const int* in_sizes, int n_in,
                              void* d_out, int out_size, void* d_ws, size_t ws_size,
                              hipStream_t stream) {
  const float* x        = (const float*)d_in[0];
  const float* Wo1      = (const float*)d_in[1];
  const float* bo1      = (const float*)d_in[2];
  const float* Wo2      = (const float*)d_in[3];
  const float* Wdw      = (const float*)d_in[4];
  const float* bn_gamma = (const float*)d_in[5];
  const float* bn_beta  = (const float*)d_in[6];
  const float* bn_mean  = (const float*)d_in[7];
  const float* bn_var   = (const float*)d_in[8];
  const float* Wpw      = (const float*)d_in[9];
  const float* bpw      = (const float*)d_in[10];
  float* out = (float*)d_out;

  float* ws = (float*)d_ws;
  float* off1        = ws + WS_OFF1;
  float* coords      = ws + WS_COORDS;
  _Float16* wpwH     = (_Float16*)(ws + WS_WPWH);
  float* wo1T        = ws + WS_WO1T;
  float* wo2T        = ws + WS_WO2T;
  float* wdwS        = ws + WS_WDWS;
  float* bias2       = ws + WS_BIAS2;

  // tiered y placement: full/mid tiers use dedicated space; small tier
  // aliases the off1 region (dead after k_coords) -> proven 37.8 MB footprint
  int chunk;
  _Float16* y;
  if (ws_size >= NEED_FULL)      { chunk = 16; y = (_Float16*)(ws + WS_Y); }
  else if (ws_size >= NEED_MID)  { chunk = 8;  y = (_Float16*)(ws + WS_Y); }
  else                           { chunk = 2;  y = (_Float16*)(ws + WS_OFF1); }

  k_prep  <<<(PREP_N + 255) / 256, 256, 0, stream>>>(
      Wpw, Wo1, Wo2, Wdw, bn_gamma, bn_beta, bn_mean, bn_var,
      wpwH, wo1T, wo2T, wdwS, bias2);
  k_off1  <<<(B_ * HW_) / 256, 256, 0, stream>>>(x, wo1T, bo1, off1);
  k_coords<<<(B_ * HW_) / 256, 256, 0, stream>>>(off1, wo2T, coords);
  for (int c0 = 0; c0 < B_; c0 += chunk) {
    k_sample<<<chunk * TILES, 256, 0, stream>>>(x, coords, wdwS, bias2, y,
                                                c0, chunk);
    k_gemm  <<<chunk * TILES, 256, 0, stream>>>(y, wpwH, bpw, out, c0, chunk);
  }
}

// Round 10
// 362.569 us; speedup vs baseline: 1.3997x; 1.0706x over previous
//
#include <hip/hip_runtime.h>
#include <math.h>

typedef _Float16 f16x8 __attribute__((ext_vector_type(8)));
typedef _Float16 f16x2 __attribute__((ext_vector_type(2)));
typedef float f32x4 __attribute__((ext_vector_type(4)));

namespace {
constexpr int B_ = 16, C_ = 128, H_ = 96, W_ = 96;
constexpr int HW_ = H_ * W_;      // 9216
constexpr int G_ = 4, S_ = 2;
constexpr int CO_ = 32;
constexpr int COUT_ = 64;
constexpr int HO_ = 192, WO_ = 192;
constexpr int HWO_ = HO_ * WO_;   // 36864
constexpr int CPG_ = C_ / G_;     // 32
constexpr int TH_ = 8, TW_ = 32;
constexpr int HALO_H = TH_ + 2, HALO_W = TW_ + 2;
constexpr int NPOS = HALO_H * HALO_W;   // 340
constexpr int TILES = (WO_ / TW_) * (HO_ / TH_);  // 144
constexpr int BPI = HW_ / 256;    // 36 blocks per image for the 96x96 kernels

// ws float offsets
constexpr size_t WS_OFF1T  = 0;                           // f16[16*9216*32] -> 2359296 f
constexpr size_t WS_COORDS = 2359296;                     // f32[16*4*HWO*2] -> 4718592 f
constexpr size_t WS_WPWH   = WS_COORDS + 4718592;         // f16[64*128]  -> 4096 f
constexpr size_t WS_WO1H   = WS_WPWH + 4096;              // f16[32*128]  -> 2048 f
constexpr size_t WS_WO2H   = WS_WO1H + 2048;              // f16[32*288]  -> 4608 f
constexpr size_t WS_WDWS   = WS_WO2H + 4608;              // f32[9*128]
constexpr size_t WS_BIAS2  = WS_WDWS + 1152;              // f32[128]
constexpr size_t WS_Y      = WS_BIAS2 + 128;              // 7089920 f
constexpr size_t Y_FULL_F  = (size_t)B_ * G_ * HWO_ * CPG_ / 2;   // 37748736 f
constexpr size_t NEED_FULL = (WS_Y + Y_FULL_F) * 4;       // ~179.4 MB
constexpr size_t NEED_MID  = (WS_Y + Y_FULL_F / 2) * 4;   // ~103.9 MB

constexpr int PREP_N = 8192 + 4096 + 9216 + 1152 + 128;   // 22784
}

// --- Kernel P: fp16 casts (Wpw, Wo1, Wo2 k-reordered) + BN-folded dw ---
__global__ __launch_bounds__(256) void k_prep(
    const float* __restrict__ Wpw, const float* __restrict__ Wo1,
    const float* __restrict__ Wo2, const float* __restrict__ Wdw,
    const float* __restrict__ bn_gamma, const float* __restrict__ bn_beta,
    const float* __restrict__ bn_mean, const float* __restrict__ bn_var,
    _Float16* __restrict__ wpwH, _Float16* __restrict__ wo1H,
    _Float16* __restrict__ wo2H, float* __restrict__ wdwS,
    float* __restrict__ bias2) {
  int i = blockIdx.x * 256 + threadIdx.x;
  if (i < 8192) {
    wpwH[i] = (_Float16)Wpw[i];
  } else if (i < 8192 + 4096) {
    int j = i - 8192;
    wo1H[j] = (_Float16)Wo1[j];                 // keep [o][c]
  } else if (i < 8192 + 4096 + 9216) {
    int j = i - 8192 - 4096;                    // dst [o][tap*32+ci]
    int o = j / 288, r = j % 288;
    int tap = r / 32, ci = r % 32;
    wo2H[j] = (_Float16)Wo2[o * 288 + ci * 9 + tap];
  } else if (i < 8192 + 4096 + 9216 + 1152) {
    int j = i - 8192 - 4096 - 9216;             // Wdw is [c][9]
    int c = j / 9, t = j % 9;
    float sc = bn_gamma[c] * rsqrtf(bn_var[c] + 1e-5f);
    wdwS[t * C_ + c] = Wdw[j] * sc;
  } else if (i < PREP_N) {
    int c = i - (8192 + 4096 + 9216 + 1152);
    float sc = bn_gamma[c] * rsqrtf(bn_var[c] + 1e-5f);
    bias2[c] = bn_beta[c] - bn_mean[c] * sc;
  }
}

// --- Kernel A (MFMA): 1x1 conv 128->32 + bias -> off1t[b][px][32] fp16 ---
__global__ __launch_bounds__(256, 4) void k_off1m(
    const float* __restrict__ x, const _Float16* __restrict__ wo1H,
    const float* __restrict__ bo1, _Float16* __restrict__ off1t) {
  __shared__ float clds[32][257];
  int bid = blockIdx.x;                       // 576, %8==0
  int swz = (bid & 7) * (B_ * BPI / 8) + (bid >> 3);
  int b = swz / BPI, p0 = (swz % BPI) * 256;
  int tid = threadIdx.x;
  int lane = tid & 63, wv_ = tid >> 6;
  int lr = lane & 15, lk = lane >> 4;

  f32x4 acc[4][2];
#pragma unroll
  for (int mt = 0; mt < 4; ++mt)
#pragma unroll
    for (int nt = 0; nt < 2; ++nt) acc[mt][nt] = (f32x4){0.f, 0.f, 0.f, 0.f};

  const float* xb = x + (size_t)b * C_ * HW_ + p0;
#pragma unroll
  for (int kk = 0; kk < 4; ++kk) {
    f16x8 afr[4];
#pragma unroll
    for (int mt = 0; mt < 4; ++mt) {
      const float* xp = xb + (size_t)(kk * 32 + lk * 8) * HW_ +
                        (wv_ * 4 + mt) * 16 + lr;
      f16x8 a;
#pragma unroll
      for (int j = 0; j < 8; ++j) a[j] = (_Float16)xp[(size_t)j * HW_];
      afr[mt] = a;
    }
#pragma unroll
    for (int nt = 0; nt < 2; ++nt) {
      f16x8 bfr = *(const f16x8*)&wo1H[(nt * 16 + lr) * C_ + kk * 32 + lk * 8];
#pragma unroll
      for (int mt = 0; mt < 4; ++mt)
        acc[mt][nt] = __builtin_amdgcn_mfma_f32_16x16x32_f16(afr[mt], bfr,
                                                             acc[mt][nt], 0, 0, 0);
    }
  }
#pragma unroll
  for (int nt = 0; nt < 2; ++nt)
#pragma unroll
    for (int mt = 0; mt < 4; ++mt)
#pragma unroll
      for (int r = 0; r < 4; ++r)
        clds[nt * 16 + lr][(wv_ * 4 + mt) * 16 + lk * 4 + r] = acc[mt][nt][r];
  __syncthreads();
  _Float16* orow = off1t + ((size_t)b * HW_ + p0 + tid) * 32;
#pragma unroll
  for (int q = 0; q < 4; ++q) {
    f16x8 v;
#pragma unroll
    for (int j = 0; j < 8; ++j)
      v[j] = (_Float16)(clds[q * 8 + j][tid] + bo1[q * 8 + j]);
    *(f16x8*)&orow[q * 8] = v;   // 64B/thread contiguous
  }
}

// --- Kernel B (MFMA): 3x3 dil(2) conv (K=9 taps x 32) -> sample coords ---
__global__ __launch_bounds__(256, 4) void k_coordsm(
    const _Float16* __restrict__ off1t, const _Float16* __restrict__ wo2H,
    float* __restrict__ coords) {
  __shared__ float clds[32][257];
  int bid = blockIdx.x;
  int swz = (bid & 7) * (B_ * BPI / 8) + (bid >> 3);
  int b = swz / BPI, p0 = (swz % BPI) * 256;
  int tid = threadIdx.x;
  int lane = tid & 63, wv_ = tid >> 6;
  int lr = lane & 15, lk = lane >> 4;

  f32x4 acc[4][2];
#pragma unroll
  for (int mt = 0; mt < 4; ++mt)
#pragma unroll
    for (int nt = 0; nt < 2; ++nt) acc[mt][nt] = (f32x4){0.f, 0.f, 0.f, 0.f};

  const _Float16* ob = off1t + (size_t)b * HW_ * 32;
  int hh[4], ww[4];
#pragma unroll
  for (int mt = 0; mt < 4; ++mt) {
    int px = p0 + (wv_ * 4 + mt) * 16 + lr;
    hh[mt] = px / W_;
    ww[mt] = px % W_;
  }
#pragma unroll
  for (int tap = 0; tap < 9; ++tap) {
    int dy2 = (tap / 3 - 1) * 2, dx2 = (tap % 3 - 1) * 2;
    f16x8 afr[4];
#pragma unroll
    for (int mt = 0; mt < 4; ++mt) {
      int h2 = hh[mt] + dy2, w2 = ww[mt] + dx2;
      f16x8 a = {};
      if ((unsigned)h2 < (unsigned)H_ && (unsigned)w2 < (unsigned)W_)
        a = *(const f16x8*)&ob[(size_t)(h2 * W_ + w2) * 32 + lk * 8];
      afr[mt] = a;
    }
#pragma unroll
    for (int nt = 0; nt < 2; ++nt) {
      f16x8 bfr = *(const f16x8*)&wo2H[(nt * 16 + lr) * 288 + tap * 32 + lk * 8];
#pragma unroll
      for (int mt = 0; mt < 4; ++mt)
        acc[mt][nt] = __builtin_amdgcn_mfma_f32_16x16x32_f16(afr[mt], bfr,
                                                             acc[mt][nt], 0, 0, 0);
    }
  }
#pragma unroll
  for (int nt = 0; nt < 2; ++nt)
#pragma unroll
    for (int mt = 0; mt < 4; ++mt)
#pragma unroll
      for (int r = 0; r < 4; ++r)
        clds[nt * 16 + lr][(wv_ * 4 + mt) * 16 + lk * 4 + r] = acc[mt][nt][r];
  __syncthreads();

  int px = p0 + tid;
  int h = px / W_, w = px % W_;
  float cwv = (float)w + sinf((float)M_PI * (float)(w + 1) / (float)W_);
  float chv = (float)h + sinf((float)M_PI * (float)(h + 1) / (float)H_);
  float* cb = coords + (size_t)b * G_ * HWO_ * 2;
#pragma unroll
  for (int g = 0; g < G_; ++g) {
#pragma unroll
    for (int sh = 0; sh < S_; ++sh) {
#pragma unroll
      for (int sw = 0; sw < S_; ++sw) {
        int idx = g * 4 + sh * 2 + sw;
        float offx = clds[idx][tid] * 0.25f + (sw ? 0.25f : -0.25f);
        float offy = clds[16 + idx][tid] * 0.25f + (sh ? 0.25f : -0.25f);
        float ix = fminf(fmaxf(cwv + offx - 0.5f, 0.f), (float)(W_ - 1));
        float iy = fminf(fmaxf(chv + offy - 0.5f, 0.f), (float)(H_ - 1));
        float2* dst = (float2*)(cb + (((size_t)g * HO_ + 2 * h + sh) * WO_
                                      + 2 * w + sw) * 2);
        *dst = (float2){ix, iy};
      }
    }
  }
}

// --- Kernel S: grid_sample + dw3x3 + BN + ReLU -> y[b][g][pix][32] fp16 ---
// up quarter-major [4][NPOS][8] f16: 16B rows -> aligned conflict-free b128.
__global__ __launch_bounds__(256, 7) void k_sample(
    const float* __restrict__ x, const float* __restrict__ coords,
    const float* __restrict__ wdwS, const float* __restrict__ bias2,
    _Float16* __restrict__ y, int b0, int nimg) {
  __shared__ __align__(16) _Float16 up4[4 * NPOS * 8];  // 21760 B

  int NWG = nimg * TILES;
  int bid = blockIdx.x;
  int swz = (bid & 7) * (NWG >> 3) + (bid >> 3);  // NWG % 8 == 0 always
  int bl = swz / TILES;
  int b = b0 + bl;
  int t = swz % TILES;
  int oh0 = (t / (WO_ / TW_)) * TH_;
  int ow0 = (t % (WO_ / TW_)) * TW_;
  int tid = threadIdx.x;
  int py = tid >> 5, px = tid & 31;
  int p_out = (oh0 + py) * WO_ + ow0 + px;

  for (int g = 0; g < G_; ++g) {
    __syncthreads();  // protects up4 reuse across g
    const float* xg = x + ((size_t)b * C_ + g * CPG_) * HW_;
    const float* cbase = coords + (((size_t)b * G_ + g) * HWO_) * 2;
    // ---- sampling: work item = (halo position, channel-octet) ----
    for (int wi = tid; wi < NPOS * 4; wi += 256) {
      int p = wi >> 2, cq = wi & 3;
      int hy = oh0 + p / HALO_W - 1;
      int hx = ow0 + p % HALO_W - 1;
      f16x8 v = {};
      if (hy >= 0 && hy < HO_ && hx >= 0 && hx < WO_) {
        float2 c2 = *(const float2*)&cbase[((size_t)hy * WO_ + hx) * 2];
        float ix = c2.x, iy = c2.y;
        float x0f = floorf(ix), y0f = floorf(iy);
        float wx = ix - x0f, wy = iy - y0f;
        int x0 = (int)x0f, y0 = (int)y0f;  // already in [0, 95]
        int x1 = min(x0 + 1, W_ - 1);
        int y1 = min(y0 + 1, H_ - 1);
        float w00 = (1.f - wx) * (1.f - wy);
        float w01 = wx * (1.f - wy);
        float w10 = (1.f - wx) * wy;
        float w11 = wx * wy;
        const float* r0 = xg + (size_t)(cq * 8) * HW_ + y0 * W_;
        const float* r1 = xg + (size_t)(cq * 8) * HW_ + y1 * W_;
#pragma unroll
        for (int j = 0; j < 8; ++j) {
          int off = j * HW_;
          v[j] = (_Float16)(w00 * r0[off + x0] + w01 * r0[off + x1] +
                            w10 * r1[off + x0] + w11 * r1[off + x1]);
        }
      }
      *(f16x8*)&up4[((size_t)cq * NPOS + p) * 8] = v;  // aligned b128 store
    }
    __syncthreads();

    // ---- dw3x3+BN+ReLU: 4 quarters x 8 channels, b128 LDS reads ----
    size_t ybase = ((size_t)(bl * G_ + g) * HWO_ + p_out) * (size_t)CPG_;
#pragma unroll
    for (int q = 0; q < 4; ++q) {
      const float4* b4 = (const float4*)&bias2[g * CPG_ + q * 8];  // s_load
      float4 ba = b4[0], bb = b4[1];
      float dwv[8] = {ba.x, ba.y, ba.z, ba.w, bb.x, bb.y, bb.z, bb.w};
#pragma unroll
      for (int tt = 0; tt < 9; ++tt) {
        int dy = tt / 3, dx = tt % 3;
        f16x8 pk = *(const f16x8*)
            &up4[((size_t)q * NPOS + (py + dy) * HALO_W + px + dx) * 8];
        const float4* w4 = (const float4*)&wdwS[tt * C_ + g * CPG_ + q * 8];
        float4 wa = w4[0], wb = w4[1];
        dwv[0] = fmaf((float)pk[0], wa.x, dwv[0]);
        dwv[1] = fmaf((float)pk[1], wa.y, dwv[1]);
        dwv[2] = fmaf((float)pk[2], wa.z, dwv[2]);
        dwv[3] = fmaf((float)pk[3], wa.w, dwv[3]);
        dwv[4] = fmaf((float)pk[4], wb.x, dwv[4]);
        dwv[5] = fmaf((float)pk[5], wb.y, dwv[5]);
        dwv[6] = fmaf((float)pk[6], wb.z, dwv[6]);
        dwv[7] = fmaf((float)pk[7], wb.w, dwv[7]);
      }
      f16x8 yv;
#pragma unroll
      for (int j = 0; j < 8; ++j) yv[j] = (_Float16)fmaxf(dwv[j], 0.f);
      *(f16x8*)&y[ybase + q * 8] = yv;
    }
  }
}

// --- Kernel G: streaming GEMM y[pix][128] @ W[128][64] -> out ---
__global__ __launch_bounds__(256, 4) void k_gemm(
    const _Float16* __restrict__ y, const _Float16* __restrict__ wpwH,
    const float* __restrict__ bpw, float* __restrict__ out, int b0, int nimg) {
  __shared__ float clds16[16][257];

  int NWG = nimg * TILES;
  int bid = blockIdx.x;
  int swz = (bid & 7) * (NWG >> 3) + (bid >> 3);
  int bl = swz / TILES;
  int b = b0 + bl;
  int p0 = (swz % TILES) * 256;
  int tid = threadIdx.x;
  int lane = tid & 63, wv_ = tid >> 6;
  int lr = lane & 15, lk = lane >> 4;

  f32x4 acc[4][4];
#pragma unroll
  for (int mt = 0; mt < 4; ++mt)
#pragma unroll
    for (int nt = 0; nt < 4; ++nt) acc[mt][nt] = (f32x4){0.f, 0.f, 0.f, 0.f};

  const _Float16* ybl = y + (size_t)bl * G_ * HWO_ * CPG_;
#pragma unroll
  for (int kk = 0; kk < 4; ++kk) {
    f16x8 afr[4];
#pragma unroll
    for (int mt = 0; mt < 4; ++mt)
      afr[mt] = *(const f16x8*)&ybl[((size_t)kk * HWO_ + p0 +
                                     (wv_ * 4 + mt) * 16 + lr) * CPG_ + lk * 8];
#pragma unroll
    for (int nt = 0; nt < 4; ++nt) {
      f16x8 bfr = *(const f16x8*)&wpwH[(nt * 16 + lr) * C_ + kk * CPG_ + lk * 8];
#pragma unroll
      for (int mt = 0; mt < 4; ++mt)
        acc[mt][nt] = __builtin_amdgcn_mfma_f32_16x16x32_f16(afr[mt], bfr,
                                                             acc[mt][nt], 0, 0, 0);
    }
  }
#pragma unroll
  for (int hq = 0; hq < 4; ++hq) {
    if (hq) __syncthreads();
#pragma unroll
    for (int mt = 0; mt < 4; ++mt) {
#pragma unroll
      for (int r = 0; r < 4; ++r)
        clds16[lr][(wv_ * 4 + mt) * 16 + lk * 4 + r] = acc[mt][hq][r];
    }
    __syncthreads();
#pragma unroll
    for (int i = 0; i < 16; ++i) {
      int o = hq * 16 + i;
      out[((size_t)b * COUT_ + o) * HWO_ + p0 + tid] = clds16[i][tid] + bpw[o];
    }
  }
}

extern "C" void kernel_launch(void* const* d_in, const int* in_sizes, int n_in,
                              void* d_out, int out_size, void* d_ws, size_t ws_size,
                              hipStream_t stream) {
  const float* x        = (const float*)d_in[0];
  const float* Wo1      = (const float*)d_in[1];
  const float* bo1      = (const float*)d_in[2];
  const float* Wo2      = (const float*)d_in[3];
  const float* Wdw      = (const float*)d_in[4];
  const float* bn_gamma = (const float*)d_in[5];
  const float* bn_beta  = (const float*)d_in[6];
  const float* bn_mean  = (const float*)d_in[7];
  const float* bn_var   = (const float*)d_in[8];
  const float* Wpw      = (const float*)d_in[9];
  const float* bpw      = (const float*)d_in[10];
  float* out = (float*)d_out;

  float* ws = (float*)d_ws;
  _Float16* off1t  = (_Float16*)(ws + WS_OFF1T);
  float* coords    = ws + WS_COORDS;
  _Float16* wpwH   = (_Float16*)(ws + WS_WPWH);
  _Float16* wo1H   = (_Float16*)(ws + WS_WO1H);
  _Float16* wo2H   = (_Float16*)(ws + WS_WO2H);
  float* wdwS      = ws + WS_WDWS;
  float* bias2     = ws + WS_BIAS2;

  // y tiers: full/mid use dedicated region; small tier (1 img) aliases
  // off1t (dead after k_coordsm; 1-img y == off1t size exactly).
  int chunk;
  _Float16* yb;
  if (ws_size >= NEED_FULL)      { chunk = 16; yb = (_Float16*)(ws + WS_Y); }
  else if (ws_size >= NEED_MID)  { chunk = 8;  yb = (_Float16*)(ws + WS_Y); }
  else                           { chunk = 1;  yb = (_Float16*)(ws + WS_OFF1T); }

  k_prep   <<<(PREP_N + 255) / 256, 256, 0, stream>>>(
      Wpw, Wo1, Wo2, Wdw, bn_gamma, bn_beta, bn_mean, bn_var,
      wpwH, wo1H, wo2H, wdwS, bias2);
  k_off1m  <<<B_ * BPI, 256, 0, stream>>>(x, wo1H, bo1, off1t);
  k_coordsm<<<B_ * BPI, 256, 0, stream>>>(off1t, wo2H, coords);
  for (int c0 = 0; c0 < B_; c0 += chunk) {
    k_sample<<<chunk * TILES, 256, 0, stream>>>(x, coords, wdwS, bias2, yb,
                                                c0, chunk);
    k_gemm  <<<chunk * TILES, 256, 0, stream>>>(yb, wpwH, bpw, out, c0, chunk);
  }
}

// Round 12
// 215.655 us; speedup vs baseline: 2.3532x; 1.6812x over previous
//
#include <hip/hip_runtime.h>
#include <math.h>

typedef _Float16 f16x8 __attribute__((ext_vector_type(8)));
typedef _Float16 f16x2 __attribute__((ext_vector_type(2)));
typedef float f32x4 __attribute__((ext_vector_type(4)));

namespace {
constexpr int B_ = 16, C_ = 128, H_ = 96, W_ = 96;
constexpr int HW_ = H_ * W_;      // 9216
constexpr int G_ = 4, S_ = 2;
constexpr int CO_ = 32;
constexpr int COUT_ = 64;
constexpr int HO_ = 192, WO_ = 192;
constexpr int HWO_ = HO_ * WO_;   // 36864
constexpr int CPG_ = C_ / G_;     // 32
constexpr int TH_ = 8, TW_ = 32;
constexpr int HALO_H = TH_ + 2, HALO_W = TW_ + 2;
constexpr int NPOS = HALO_H * HALO_W;   // 340
constexpr int TILES = (WO_ / TW_) * (HO_ / TH_);  // 144
constexpr int BPI = HW_ / 256;    // 36 blocks/image for 96x96 MFMA kernels
constexpr int XPB = HW_ / 64;     // 144 transpose blocks/image

// ws float offsets  (f16[N] occupies N/2 floats — R11 bug was N/4)
constexpr size_t WS_XT     = 0;                    // f16[18874368] = 9437184 f
constexpr size_t WS_OFF1T  = 9437184;              // f16[4718592]  = 2359296 f
constexpr size_t WS_COORDS = 11796480;             // f32[4718592]
constexpr size_t WS_WPWH   = 16515072;             // f16[8192] = 4096 f
constexpr size_t WS_WO1H   = 16519168;             // f16[4096] = 2048 f
constexpr size_t WS_WO2H   = 16521216;             // f16[9216] = 4608 f
constexpr size_t WS_WDWS   = 16525824;             // f32[1152]
constexpr size_t WS_BIAS2  = 16526976;             // f32[128]
constexpr size_t WS_Y      = 16527104;
constexpr size_t Y_FULL_F  = (size_t)B_ * G_ * HWO_ * CPG_ / 2;   // 37748736 f
constexpr size_t NEED_FULL = (WS_Y + Y_FULL_F) * 4;       // ~217.1 MB
constexpr size_t NEED_MID  = (WS_Y + Y_FULL_F / 2) * 4;   // ~141.6 MB

constexpr int PREP_N = 8192 + 4096 + 9216 + 1152 + 128;   // 22784
}

// --- Kernel P: fp16 casts (Wpw, Wo1, Wo2 k-reordered) + BN-folded dw ---
__global__ __launch_bounds__(256) void k_prep(
    const float* __restrict__ Wpw, const float* __restrict__ Wo1,
    const float* __restrict__ Wo2, const float* __restrict__ Wdw,
    const float* __restrict__ bn_gamma, const float* __restrict__ bn_beta,
    const float* __restrict__ bn_mean, const float* __restrict__ bn_var,
    _Float16* __restrict__ wpwH, _Float16* __restrict__ wo1H,
    _Float16* __restrict__ wo2H, float* __restrict__ wdwS,
    float* __restrict__ bias2) {
  int i = blockIdx.x * 256 + threadIdx.x;
  if (i < 8192) {
    wpwH[i] = (_Float16)Wpw[i];
  } else if (i < 8192 + 4096) {
    int j = i - 8192;
    wo1H[j] = (_Float16)Wo1[j];                 // keep [o][c]
  } else if (i < 8192 + 4096 + 9216) {
    int j = i - 8192 - 4096;                    // dst [o][tap*32+ci]
    int o = j / 288, r = j % 288;
    int tap = r / 32, ci = r % 32;
    wo2H[j] = (_Float16)Wo2[o * 288 + ci * 9 + tap];
  } else if (i < 8192 + 4096 + 9216 + 1152) {
    int j = i - 8192 - 4096 - 9216;             // Wdw is [c][9]
    int c = j / 9, t = j % 9;
    float sc = bn_gamma[c] * rsqrtf(bn_var[c] + 1e-5f);
    wdwS[t * C_ + c] = Wdw[j] * sc;
  } else if (i < PREP_N) {
    int c = i - (8192 + 4096 + 9216 + 1152);
    float sc = bn_gamma[c] * rsqrtf(bn_var[c] + 1e-5f);
    bias2[c] = bn_beta[c] - bn_mean[c] * sc;
  }
}

// --- Kernel X: transpose x [b][c][px] f32 -> xT [b][px][c] f16 ---
__global__ __launch_bounds__(256, 4) void k_xpose(const float* __restrict__ x,
                                                  _Float16* __restrict__ xT) {
  __shared__ float t[64][130];
  int bid = blockIdx.x;                       // B*XPB = 2304, %8==0
  int swz = (bid & 7) * (B_ * XPB / 8) + (bid >> 3);
  int b = swz / XPB, px0 = (swz % XPB) * 64;
  int tid = threadIdx.x;
  int lane = tid & 63, wv = tid >> 6;
  const float* xb = x + (size_t)b * C_ * HW_ + px0 + lane;
  for (int c = wv; c < C_; c += 4) t[lane][c] = xb[(size_t)c * HW_];
  __syncthreads();
  _Float16* ob = xT + ((size_t)b * HW_ + px0) * C_;
#pragma unroll
  for (int k = 0; k < 4; ++k) {
    int cid = tid + 256 * k;
    int px = cid >> 4, part = cid & 15;
    f16x8 v;
#pragma unroll
    for (int j = 0; j < 8; ++j) v[j] = (_Float16)t[px][part * 8 + j];
    *(f16x8*)&ob[(size_t)px * C_ + part * 8] = v;
  }
}

// --- Kernel A (MFMA): 1x1 conv 128->32 + bias -> off1t[b][px][32] fp16 ---
__global__ __launch_bounds__(256, 4) void k_off1m(
    const _Float16* __restrict__ xT, const _Float16* __restrict__ wo1H,
    const float* __restrict__ bo1, _Float16* __restrict__ off1t) {
  __shared__ float clds[32][257];
  int bid = blockIdx.x;                       // 576, %8==0
  int swz = (bid & 7) * (B_ * BPI / 8) + (bid >> 3);
  int b = swz / BPI, p0 = (swz % BPI) * 256;
  int tid = threadIdx.x;
  int lane = tid & 63, wv_ = tid >> 6;
  int lr = lane & 15, lk = lane >> 4;

  f32x4 acc[4][2];
#pragma unroll
  for (int mt = 0; mt < 4; ++mt)
#pragma unroll
    for (int nt = 0; nt < 2; ++nt) acc[mt][nt] = (f32x4){0.f, 0.f, 0.f, 0.f};

  const _Float16* xb = xT + ((size_t)b * HW_ + p0) * C_;
#pragma unroll
  for (int kk = 0; kk < 4; ++kk) {
    f16x8 afr[4];
#pragma unroll
    for (int mt = 0; mt < 4; ++mt)
      afr[mt] = *(const f16x8*)&xb[(size_t)((wv_ * 4 + mt) * 16 + lr) * C_ +
                                   kk * 32 + lk * 8];
#pragma unroll
    for (int nt = 0; nt < 2; ++nt) {
      f16x8 bfr = *(const f16x8*)&wo1H[(nt * 16 + lr) * C_ + kk * 32 + lk * 8];
#pragma unroll
      for (int mt = 0; mt < 4; ++mt)
        acc[mt][nt] = __builtin_amdgcn_mfma_f32_16x16x32_f16(afr[mt], bfr,
                                                             acc[mt][nt], 0, 0, 0);
    }
  }
#pragma unroll
  for (int nt = 0; nt < 2; ++nt)
#pragma unroll
    for (int mt = 0; mt < 4; ++mt)
#pragma unroll
      for (int r = 0; r < 4; ++r)
        clds[nt * 16 + lr][(wv_ * 4 + mt) * 16 + lk * 4 + r] = acc[mt][nt][r];
  __syncthreads();
  _Float16* orow = off1t + ((size_t)b * HW_ + p0 + tid) * 32;
#pragma unroll
  for (int q = 0; q < 4; ++q) {
    f16x8 v;
#pragma unroll
    for (int j = 0; j < 8; ++j)
      v[j] = (_Float16)(clds[q * 8 + j][tid] + bo1[q * 8 + j]);
    *(f16x8*)&orow[q * 8] = v;   // 64B/thread contiguous
  }
}

// --- Kernel B (MFMA): 3x3 dil(2) conv (K=9 taps x 32) -> sample coords ---
__global__ __launch_bounds__(256, 4) void k_coordsm(
    const _Float16* __restrict__ off1t, const _Float16* __restrict__ wo2H,
    float* __restrict__ coords) {
  __shared__ float clds[32][257];
  int bid = blockIdx.x;
  int swz = (bid & 7) * (B_ * BPI / 8) + (bid >> 3);
  int b = swz / BPI, p0 = (swz % BPI) * 256;
  int tid = threadIdx.x;
  int lane = tid & 63, wv_ = tid >> 6;
  int lr = lane & 15, lk = lane >> 4;

  f32x4 acc[4][2];
#pragma unroll
  for (int mt = 0; mt < 4; ++mt)
#pragma unroll
    for (int nt = 0; nt < 2; ++nt) acc[mt][nt] = (f32x4){0.f, 0.f, 0.f, 0.f};

  const _Float16* ob = off1t + (size_t)b * HW_ * 32;
  int hh[4], ww[4];
#pragma unroll
  for (int mt = 0; mt < 4; ++mt) {
    int px = p0 + (wv_ * 4 + mt) * 16 + lr;
    hh[mt] = px / W_;
    ww[mt] = px % W_;
  }
#pragma unroll
  for (int tap = 0; tap < 9; ++tap) {
    int dy2 = (tap / 3 - 1) * 2, dx2 = (tap % 3 - 1) * 2;
    f16x8 afr[4];
#pragma unroll
    for (int mt = 0; mt < 4; ++mt) {
      int h2 = hh[mt] + dy2, w2 = ww[mt] + dx2;
      f16x8 a = {};
      if ((unsigned)h2 < (unsigned)H_ && (unsigned)w2 < (unsigned)W_)
        a = *(const f16x8*)&ob[(size_t)(h2 * W_ + w2) * 32 + lk * 8];
      afr[mt] = a;
    }
#pragma unroll
    for (int nt = 0; nt < 2; ++nt) {
      f16x8 bfr = *(const f16x8*)&wo2H[(nt * 16 + lr) * 288 + tap * 32 + lk * 8];
#pragma unroll
      for (int mt = 0; mt < 4; ++mt)
        acc[mt][nt] = __builtin_amdgcn_mfma_f32_16x16x32_f16(afr[mt], bfr,
                                                             acc[mt][nt], 0, 0, 0);
    }
  }
#pragma unroll
  for (int nt = 0; nt < 2; ++nt)
#pragma unroll
    for (int mt = 0; mt < 4; ++mt)
#pragma unroll
      for (int r = 0; r < 4; ++r)
        clds[nt * 16 + lr][(wv_ * 4 + mt) * 16 + lk * 4 + r] = acc[mt][nt][r];
  __syncthreads();

  int px = p0 + tid;
  int h = px / W_, w = px % W_;
  float cwv = (float)w + sinf((float)M_PI * (float)(w + 1) / (float)W_);
  float chv = (float)h + sinf((float)M_PI * (float)(h + 1) / (float)H_);
  float* cb = coords + (size_t)b * G_ * HWO_ * 2;
#pragma unroll
  for (int g = 0; g < G_; ++g) {
#pragma unroll
    for (int sh = 0; sh < S_; ++sh) {
#pragma unroll
      for (int sw = 0; sw < S_; ++sw) {
        int idx = g * 4 + sh * 2 + sw;
        float offx = clds[idx][tid] * 0.25f + (sw ? 0.25f : -0.25f);
        float offy = clds[16 + idx][tid] * 0.25f + (sh ? 0.25f : -0.25f);
        float ix = fminf(fmaxf(cwv + offx - 0.5f, 0.f), (float)(W_ - 1));
        float iy = fminf(fmaxf(chv + offy - 0.5f, 0.f), (float)(H_ - 1));
        float2* dst = (float2*)(cb + (((size_t)g * HO_ + 2 * h + sh) * WO_
                                      + 2 * w + sw) * 2);
        *dst = (float2){ix, iy};
      }
    }
  }
}

// --- Kernel S: grid_sample (xT gather, 4x f16x8/item) + dw3x3+BN+ReLU -> y ---
// up4 tail-padded to 23424 B LDS -> exactly 6 blocks/CU (7 thrashes L2: R10
// FETCH 47->164 MB).
__global__ __launch_bounds__(256, 6) void k_sample(
    const _Float16* __restrict__ xT, const float* __restrict__ coords,
    const float* __restrict__ wdwS, const float* __restrict__ bias2,
    _Float16* __restrict__ y, int b0, int nimg) {
  __shared__ __align__(16) _Float16 up4[4 * NPOS * 8 + 832];  // 23424 B

  int NWG = nimg * TILES;
  int bid = blockIdx.x;
  int swz = (bid & 7) * (NWG >> 3) + (bid >> 3);  // NWG % 8 == 0 always
  int bl = swz / TILES;
  int b = b0 + bl;
  int t = swz % TILES;
  int oh0 = (t / (WO_ / TW_)) * TH_;
  int ow0 = (t % (WO_ / TW_)) * TW_;
  int tid = threadIdx.x;
  int py = tid >> 5, px = tid & 31;
  int p_out = (oh0 + py) * WO_ + ow0 + px;

  const _Float16* xbase = xT + (size_t)b * HW_ * C_;
  for (int g = 0; g < G_; ++g) {
    __syncthreads();  // protects up4 reuse across g
    const float* cbase = coords + (((size_t)b * G_ + g) * HWO_) * 2;
    // ---- sampling: work item = (halo position, channel-octet) ----
    for (int wi = tid; wi < NPOS * 4; wi += 256) {
      int p = wi >> 2, cq = wi & 3;
      int hy = oh0 + p / HALO_W - 1;
      int hx = ow0 + p % HALO_W - 1;
      f16x8 v = {};
      if (hy >= 0 && hy < HO_ && hx >= 0 && hx < WO_) {
        float2 c2 = *(const float2*)&cbase[((size_t)hy * WO_ + hx) * 2];
        float ix = c2.x, iy = c2.y;
        float x0f = floorf(ix), y0f = floorf(iy);
        float wx = ix - x0f, wy = iy - y0f;
        int x0 = (int)x0f, y0 = (int)y0f;  // already in [0, 95]
        int x1 = min(x0 + 1, W_ - 1);
        int y1 = min(y0 + 1, H_ - 1);
        float w00 = (1.f - wx) * (1.f - wy);
        float w01 = wx * (1.f - wy);
        float w10 = (1.f - wx) * wy;
        float w11 = wx * wy;
        const _Float16* xc = xbase + g * CPG_ + cq * 8;
        f16x8 a00 = *(const f16x8*)&xc[(size_t)(y0 * W_ + x0) * C_];
        f16x8 a01 = *(const f16x8*)&xc[(size_t)(y0 * W_ + x1) * C_];
        f16x8 a10 = *(const f16x8*)&xc[(size_t)(y1 * W_ + x0) * C_];
        f16x8 a11 = *(const f16x8*)&xc[(size_t)(y1 * W_ + x1) * C_];
#pragma unroll
        for (int j = 0; j < 8; ++j)
          v[j] = (_Float16)(w00 * (float)a00[j] + w01 * (float)a01[j] +
                            w10 * (float)a10[j] + w11 * (float)a11[j]);
      }
      *(f16x8*)&up4[((size_t)cq * NPOS + p) * 8] = v;  // aligned b128 store
    }
    __syncthreads();

    // ---- dw3x3+BN+ReLU: 4 quarters x 8 channels, b128 LDS reads ----
    size_t ybase = ((size_t)(bl * G_ + g) * HWO_ + p_out) * (size_t)CPG_;
#pragma unroll
    for (int q = 0; q < 4; ++q) {
      const float4* b4 = (const float4*)&bias2[g * CPG_ + q * 8];  // s_load
      float4 ba = b4[0], bb = b4[1];
      float dwv[8] = {ba.x, ba.y, ba.z, ba.w, bb.x, bb.y, bb.z, bb.w};
#pragma unroll
      for (int tt = 0; tt < 9; ++tt) {
        int dy = tt / 3, dx = tt % 3;
        f16x8 pk = *(const f16x8*)
            &up4[((size_t)q * NPOS + (py + dy) * HALO_W + px + dx) * 8];
        const float4* w4 = (const float4*)&wdwS[tt * C_ + g * CPG_ + q * 8];
        float4 wa = w4[0], wb = w4[1];
        dwv[0] = fmaf((float)pk[0], wa.x, dwv[0]);
        dwv[1] = fmaf((float)pk[1], wa.y, dwv[1]);
        dwv[2] = fmaf((float)pk[2], wa.z, dwv[2]);
        dwv[3] = fmaf((float)pk[3], wa.w, dwv[3]);
        dwv[4] = fmaf((float)pk[4], wb.x, dwv[4]);
        dwv[5] = fmaf((float)pk[5], wb.y, dwv[5]);
        dwv[6] = fmaf((float)pk[6], wb.z, dwv[6]);
        dwv[7] = fmaf((float)pk[7], wb.w, dwv[7]);
      }
      f16x8 yv;
#pragma unroll
      for (int j = 0; j < 8; ++j) yv[j] = (_Float16)fmaxf(dwv[j], 0.f);
      *(f16x8*)&y[ybase + q * 8] = yv;
    }
  }
}

// --- Kernel G: streaming GEMM y[pix][128] @ W[128][64] -> out ---
__global__ __launch_bounds__(256, 4) void k_gemm(
    const _Float16* __restrict__ y, const _Float16* __restrict__ wpwH,
    const float* __restrict__ bpw, float* __restrict__ out, int b0, int nimg) {
  __shared__ float clds16[16][257];

  int NWG = nimg * TILES;
  int bid = blockIdx.x;
  int swz = (bid & 7) * (NWG >> 3) + (bid >> 3);
  int bl = swz / TILES;
  int b = b0 + bl;
  int p0 = (swz % TILES) * 256;
  int tid = threadIdx.x;
  int lane = tid & 63, wv_ = tid >> 6;
  int lr = lane & 15, lk = lane >> 4;

  f32x4 acc[4][4];
#pragma unroll
  for (int mt = 0; mt < 4; ++mt)
#pragma unroll
    for (int nt = 0; nt < 4; ++nt) acc[mt][nt] = (f32x4){0.f, 0.f, 0.f, 0.f};

  const _Float16* ybl = y + (size_t)bl * G_ * HWO_ * CPG_;
#pragma unroll
  for (int kk = 0; kk < 4; ++kk) {
    f16x8 afr[4];
#pragma unroll
    for (int mt = 0; mt < 4; ++mt)
      afr[mt] = *(const f16x8*)&ybl[((size_t)kk * HWO_ + p0 +
                                     (wv_ * 4 + mt) * 16 + lr) * CPG_ + lk * 8];
#pragma unroll
    for (int nt = 0; nt < 4; ++nt) {
      f16x8 bfr = *(const f16x8*)&wpwH[(nt * 16 + lr) * C_ + kk * CPG_ + lk * 8];
#pragma unroll
      for (int mt = 0; mt < 4; ++mt)
        acc[mt][nt] = __builtin_amdgcn_mfma_f32_16x16x32_f16(afr[mt], bfr,
                                                             acc[mt][nt], 0, 0, 0);
    }
  }
#pragma unroll
  for (int hq = 0; hq < 4; ++hq) {
    if (hq) __syncthreads();
#pragma unroll
    for (int mt = 0; mt < 4; ++mt) {
#pragma unroll
      for (int r = 0; r < 4; ++r)
        clds16[lr][(wv_ * 4 + mt) * 16 + lk * 4 + r] = acc[mt][hq][r];
    }
    __syncthreads();
#pragma unroll
    for (int i = 0; i < 16; ++i) {
      int o = hq * 16 + i;
      out[((size_t)b * COUT_ + o) * HWO_ + p0 + tid] = clds16[i][tid] + bpw[o];
    }
  }
}

extern "C" void kernel_launch(void* const* d_in, const int* in_sizes, int n_in,
                              void* d_out, int out_size, void* d_ws, size_t ws_size,
                              hipStream_t stream) {
  const float* x        = (const float*)d_in[0];
  const float* Wo1      = (const float*)d_in[1];
  const float* bo1      = (const float*)d_in[2];
  const float* Wo2      = (const float*)d_in[3];
  const float* Wdw      = (const float*)d_in[4];
  const float* bn_gamma = (const float*)d_in[5];
  const float* bn_beta  = (const float*)d_in[6];
  const float* bn_mean  = (const float*)d_in[7];
  const float* bn_var   = (const float*)d_in[8];
  const float* Wpw      = (const float*)d_in[9];
  const float* bpw      = (const float*)d_in[10];
  float* out = (float*)d_out;

  float* ws = (float*)d_ws;
  _Float16* xT     = (_Float16*)(ws + WS_XT);
  _Float16* off1t  = (_Float16*)(ws + WS_OFF1T);
  float* coords    = ws + WS_COORDS;
  _Float16* wpwH   = (_Float16*)(ws + WS_WPWH);
  _Float16* wo1H   = (_Float16*)(ws + WS_WO1H);
  _Float16* wo2H   = (_Float16*)(ws + WS_WO2H);
  float* wdwS      = ws + WS_WDWS;
  float* bias2     = ws + WS_BIAS2;

  // y tiers: full/mid use dedicated region; small tier (1 img) aliases
  // off1t (dead after k_coordsm; 1-img y fits in off1t region exactly).
  int chunk;
  _Float16* yb;
  if (ws_size >= NEED_FULL)      { chunk = 16; yb = (_Float16*)(ws + WS_Y); }
  else if (ws_size >= NEED_MID)  { chunk = 8;  yb = (_Float16*)(ws + WS_Y); }
  else                           { chunk = 1;  yb = (_Float16*)(ws + WS_OFF1T); }

  k_prep   <<<(PREP_N + 255) / 256, 256, 0, stream>>>(
      Wpw, Wo1, Wo2, Wdw, bn_gamma, bn_beta, bn_mean, bn_var,
      wpwH, wo1H, wo2H, wdwS, bias2);
  k_xpose  <<<B_ * XPB, 256, 0, stream>>>(x, xT);
  k_off1m  <<<B_ * BPI, 256, 0, stream>>>(xT, wo1H, bo1, off1t);
  k_coordsm<<<B_ * BPI, 256, 0, stream>>>(off1t, wo2H, coords);
  for (int c0 = 0; c0 < B_; c0 += chunk) {
    k_sample<<<chunk * TILES, 256, 0, stream>>>(xT, coords, wdwS, bias2, yb,
                                                c0, chunk);
    k_gemm  <<<chunk * TILES, 256, 0, stream>>>(yb, wpwH, bpw, out, c0, chunk);
  }
}